// Round 7
// baseline (326.708 us; speedup 1.0000x reference)
//
#include <hip/hip_runtime.h>
#include <hip/hip_bf16.h>
#include <math.h>

typedef __hip_bfloat16 bf16;

#define NPB 784                    // nodes per bucket == nodes per image
#define SRC_BITS 21
#define SRC_MASK ((1u << SRC_BITS) - 1u)
#define NB_MAX 2048                // max buckets the LDS kernels support
#define SCAP 16                    // staging slots per bucket (LDS)
#define FCHUNK 8                   // flush granularity (32B)
#define BINBLK 256                 // blocks for hist/bin2 (fixed; scan assumes 256)

__device__ __forceinline__ float bf2f(bf16 v) { return __bfloat162float(v); }

// ---------- dtype detector ----------
__global__ void k_detect(const unsigned short* __restrict__ xr, int* __restrict__ flag) {
    if (blockIdx.x == 0 && threadIdx.x == 0) {
        int pl = 0;
        for (int i = 0; i < 64; ++i) {
            int e = (xr[i] >> 7) & 0xFF;
            if (e >= 110 && e <= 130) ++pl;
        }
        *flag = (pl >= 52) ? 1 : 0;
    }
}

// ======================= FAST PATH (counting-sort binning) =======================

// pass 1: per-(block,bucket) histogram of dst only. hist[block*nb + b].
template <bool VEC>
__global__ __launch_bounds__(1024) void k_hist(
    const int* __restrict__ dst, int* __restrict__ hist, int E, int N, int nb, int epb) {
    __shared__ int h[NB_MAX];
    int tid = threadIdx.x;
    for (int b = tid; b < nb; b += 1024) h[b] = 0;
    __syncthreads();
    int start = blockIdx.x * epb;
    int end = min(E, start + epb);
    for (int e0 = start + tid * 4; e0 < end; e0 += 4096) {
        if (VEC && (e0 + 3 < end)) {
            int4 d4 = *reinterpret_cast<const int4*>(dst + e0);
            if ((unsigned)d4.x < (unsigned)N) atomicAdd(&h[(unsigned)d4.x / (unsigned)NPB], 1);
            if ((unsigned)d4.y < (unsigned)N) atomicAdd(&h[(unsigned)d4.y / (unsigned)NPB], 1);
            if ((unsigned)d4.z < (unsigned)N) atomicAdd(&h[(unsigned)d4.z / (unsigned)NPB], 1);
            if ((unsigned)d4.w < (unsigned)N) atomicAdd(&h[(unsigned)d4.w / (unsigned)NPB], 1);
        } else {
            for (int e = e0; e < end && e < e0 + 4; ++e) {
                unsigned du = (unsigned)dst[e];
                if (du < (unsigned)N) atomicAdd(&h[du / (unsigned)NPB], 1);
            }
        }
    }
    __syncthreads();
    int* hrow = hist + (size_t)blockIdx.x * nb;
    for (int b = tid; b < nb; b += 1024) hrow[b] = h[b];
}

// scan: one wave per bucket; prefix over 256 block counts (in place),
// writes absolute start offsets; counts[b] = total edges of bucket b.
__global__ __launch_bounds__(256) void k_scan(
    int* __restrict__ hist, int* __restrict__ counts, int nb, int cap) {
    int wid = blockIdx.x * 4 + (threadIdx.x >> 6);   // bucket id
    int lane = threadIdx.x & 63;
    if (wid >= nb) return;
    int v0 = hist[(size_t)(lane * 4 + 0) * nb + wid];
    int v1 = hist[(size_t)(lane * 4 + 1) * nb + wid];
    int v2 = hist[(size_t)(lane * 4 + 2) * nb + wid];
    int v3 = hist[(size_t)(lane * 4 + 3) * nb + wid];
    int s = v0 + v1 + v2 + v3;
    int e = s;
    #pragma unroll
    for (int off = 1; off < 64; off <<= 1) {
        int t = __shfl_up(e, off, 64);
        if (lane >= off) e += t;
    }
    int total = __shfl(e, 63, 64);
    e -= s;                                           // exclusive prefix
    int p = wid * cap + e;
    hist[(size_t)(lane * 4 + 0) * nb + wid] = p; p += v0;
    hist[(size_t)(lane * 4 + 1) * nb + wid] = p; p += v1;
    hist[(size_t)(lane * 4 + 2) * nb + wid] = p; p += v2;
    hist[(size_t)(lane * 4 + 3) * nb + wid] = p;
    if (lane == 0) counts[wid] = total;
}

// pass 2: place edges; cursors live in LDS (pre-reserved exact regions).
// NOTE: every dst-valid edge is placed (src clamped) so counts match k_hist exactly.
__device__ __forceinline__ void bin_one2(int dd, int ss, int N,
                                         unsigned* stage, int* lcnt, int* lcur,
                                         unsigned* __restrict__ binned, int cap) {
    unsigned du = (unsigned)dd;
    if (du < (unsigned)N) {
        unsigned su = (unsigned)ss;
        if (su >= (unsigned)N) su = (unsigned)(N - 1);   // defensive clamp
        unsigned b  = du / (unsigned)NPB;
        unsigned lo = du - b * (unsigned)NPB;
        unsigned pk = (lo << SRC_BITS) | su;
        int idx = atomicAdd(&lcnt[b], 1);
        if (idx < SCAP) {
            stage[b * SCAP + idx] = pk;
        } else {                      // rare in-batch overflow: direct place
            int pos = atomicAdd(&lcur[b], 1);
            if (pos < (int)((b + 1) * (unsigned)cap)) binned[pos] = pk;
        }
    }
}

__device__ __forceinline__ void bin_flush2(unsigned* stage, int* lcnt, int* lcur,
                                           unsigned* __restrict__ binned,
                                           int nb, int cap, bool drain, int tid) {
    for (int b = tid; b < nb; b += 1024) {
        int c = lcnt[b];
        int valid = c < SCAP ? c : SCAP;
        int cntf = drain ? valid : (valid & ~(FCHUNK - 1));
        if (cntf > 0) {
            int pos = atomicAdd(&lcur[b], cntf);
            int lim = (b + 1) * cap;
            unsigned* s = stage + b * SCAP;
            if (((pos & 3) == 0) && (pos + cntf <= lim)) {
                int k = 0;
                for (; k + 4 <= cntf; k += 4) {
                    uint4 v; v.x = s[k]; v.y = s[k + 1]; v.z = s[k + 2]; v.w = s[k + 3];
                    *reinterpret_cast<uint4*>(binned + pos + k) = v;
                }
                for (; k < cntf; ++k) binned[pos + k] = s[k];
            } else {
                for (int k = 0; k < cntf; ++k)
                    if (pos + k < lim) binned[pos + k] = s[k];
            }
            int rem = valid - cntf;
            for (int k = 0; k < rem; ++k) s[k] = s[cntf + k];
            lcnt[b] = rem;
        }
    }
}

template <bool VEC>
__global__ __launch_bounds__(1024) void k_bin2(
    const int* __restrict__ src, const int* __restrict__ dst,
    unsigned* __restrict__ binned, const int* __restrict__ offs,
    int E, int N, int cap, int nb, int epb) {
    __shared__ unsigned stage[NB_MAX * SCAP];   // 128 KB
    __shared__ int lcnt[NB_MAX];                // 8 KB
    __shared__ int lcur[NB_MAX];                // 8 KB
    int tid = threadIdx.x;
    const int* orow = offs + (size_t)blockIdx.x * nb;
    for (int b = tid; b < nb; b += 1024) { lcnt[b] = 0; lcur[b] = orow[b]; }
    __syncthreads();
    int start = blockIdx.x * epb;
    int end = min(E, start + epb);
    if (start >= end) return;   // uniform across block

    int e_cur = start + tid * 4;
    int4 s_cur, d_cur;
    bool v_cur = VEC && (e_cur + 3 < end);
    if (v_cur) {
        s_cur = *reinterpret_cast<const int4*>(src + e_cur);
        d_cur = *reinterpret_cast<const int4*>(dst + e_cur);
    }
    for (int base_e = start; base_e < end; base_e += 4096) {
        int e_nxt = e_cur + 4096;
        int4 s_nxt, d_nxt;
        bool v_nxt = VEC && (base_e + 4096 < end) && (e_nxt + 3 < end);
        if (v_nxt) {
            s_nxt = *reinterpret_cast<const int4*>(src + e_nxt);
            d_nxt = *reinterpret_cast<const int4*>(dst + e_nxt);
        }
        if (e_cur < end) {
            if (v_cur) {
                bin_one2(d_cur.x, s_cur.x, N, stage, lcnt, lcur, binned, cap);
                bin_one2(d_cur.y, s_cur.y, N, stage, lcnt, lcur, binned, cap);
                bin_one2(d_cur.z, s_cur.z, N, stage, lcnt, lcur, binned, cap);
                bin_one2(d_cur.w, s_cur.w, N, stage, lcnt, lcur, binned, cap);
            } else {
                for (int e = e_cur; e < end && e < e_cur + 4; ++e)
                    bin_one2(dst[e], src[e], N, stage, lcnt, lcur, binned, cap);
            }
        }
        __syncthreads();
        bool last = (base_e + 4096 >= end);
        bin_flush2(stage, lcnt, lcur, binned, nb, cap, last, tid);
        __syncthreads();
        e_cur = e_nxt; s_cur = s_nxt; d_cur = d_nxt; v_cur = v_nxt;
    }
}

// ---------- consumers (one block per bucket) ----------

__global__ __launch_bounds__(256) void k_deg(
    const unsigned* __restrict__ binned, const int* __restrict__ counts,
    const void* __restrict__ xp, float* __restrict__ dinv, bf16* __restrict__ normx,
    int N, int cap, const int* __restrict__ flag) {
    __shared__ int ideg[NPB];
    int b = blockIdx.x, tid = threadIdx.x;
    for (int i = tid; i < NPB; i += 256) ideg[i] = 1;   // self-loop
    __syncthreads();
    int base = b * cap;
    int cnt = min(counts[b], cap);
    int cv = cnt & ~3;
    for (int i = tid * 4; i < cv; i += 1024) {
        uint4 p = *reinterpret_cast<const uint4*>(binned + base + i);
        atomicAdd(&ideg[p.x >> SRC_BITS], 1);
        atomicAdd(&ideg[p.y >> SRC_BITS], 1);
        atomicAdd(&ideg[p.z >> SRC_BITS], 1);
        atomicAdd(&ideg[p.w >> SRC_BITS], 1);
    }
    for (int i = cv + tid; i < cnt; i += 256)
        atomicAdd(&ideg[binned[base + i] >> SRC_BITS], 1);
    __syncthreads();
    bool isb = (*flag) != 0;
    long node0 = (long)b * NPB;
    for (int i = tid; i < NPB; i += 256) {
        long node = node0 + i;
        if (node < N) {
            float di = rsqrtf((float)ideg[i]);
            float xv = isb ? bf2f(((const bf16*)xp)[node]) : ((const float*)xp)[node];
            dinv[node] = di;
            normx[node] = __float2bfloat16(di * xv);
        }
    }
}

__global__ __launch_bounds__(256) void k_agg1(
    const unsigned* __restrict__ binned, const int* __restrict__ counts,
    const float* __restrict__ dinv, const bf16* __restrict__ normx,
    bf16* __restrict__ normh,
    const void* __restrict__ W1p, const void* __restrict__ b1p,
    const void* __restrict__ W2p, int N, int cap, const int* __restrict__ flag) {
    __shared__ float acc[NPB];
    __shared__ float sh_ab[2];
    int b = blockIdx.x, tid = threadIdx.x;
    bool isb = (*flag) != 0;
    if (tid == 0) {
        float a = 0.f, bb = 0.f;
        if (isb) {
            const bf16* W1 = (const bf16*)W1p; const bf16* b1 = (const bf16*)b1p;
            const bf16* W2 = (const bf16*)W2p;
            #pragma unroll
            for (int k = 0; k < 16; ++k) {
                float w2 = bf2f(W2[k]);
                a += bf2f(W1[k]) * w2;
                bb += bf2f(b1[k]) * w2;
            }
        } else {
            const float* W1 = (const float*)W1p; const float* b1 = (const float*)b1p;
            const float* W2 = (const float*)W2p;
            #pragma unroll
            for (int k = 0; k < 16; ++k) { a += W1[k] * W2[k]; bb += b1[k] * W2[k]; }
        }
        sh_ab[0] = a; sh_ab[1] = bb;
    }
    for (int i = tid; i < NPB; i += 256) acc[i] = 0.f;
    __syncthreads();
    int base = b * cap;
    int cnt = min(counts[b], cap);
    int cv = cnt & ~3;
    for (int i = tid * 4; i < cv; i += 1024) {
        uint4 p = *reinterpret_cast<const uint4*>(binned + base + i);
        float v0 = bf2f(normx[p.x & SRC_MASK]);
        float v1 = bf2f(normx[p.y & SRC_MASK]);
        float v2 = bf2f(normx[p.z & SRC_MASK]);
        float v3 = bf2f(normx[p.w & SRC_MASK]);
        atomicAdd(&acc[p.x >> SRC_BITS], v0);
        atomicAdd(&acc[p.y >> SRC_BITS], v1);
        atomicAdd(&acc[p.z >> SRC_BITS], v2);
        atomicAdd(&acc[p.w >> SRC_BITS], v3);
    }
    for (int i = cv + tid; i < cnt; i += 256) {
        unsigned p = binned[base + i];
        atomicAdd(&acc[p >> SRC_BITS], bf2f(normx[p & SRC_MASK]));
    }
    __syncthreads();
    float alpha = sh_ab[0], beta = sh_ab[1];
    long node0 = (long)b * NPB;
    for (int i = tid; i < NPB; i += 256) {
        long node = node0 + i;
        if (node < N) {
            float di = dinv[node];
            float s1 = bf2f(normx[node]) + acc[i];       // self + neighbors
            float h2 = fmaf(alpha, di * s1, beta);       // layer-2 pre-act
            normh[node] = __float2bfloat16(di * h2);
        }
    }
}

// layer-2 aggregation only; writes v = dinv*s2 + b2 IN PLACE over dinv[]
__global__ __launch_bounds__(256) void k_agg2(
    const unsigned* __restrict__ binned, const int* __restrict__ counts,
    float* __restrict__ dinv_v, const bf16* __restrict__ normh,
    const void* __restrict__ b2p, int N, int cap, const int* __restrict__ flag) {
    __shared__ float acc[NPB];
    int b = blockIdx.x, tid = threadIdx.x;
    bool isb = (*flag) != 0;
    for (int i = tid; i < NPB; i += 256) acc[i] = 0.f;
    __syncthreads();
    int base = b * cap;
    int cnt = min(counts[b], cap);
    int cv = cnt & ~3;
    for (int i = tid * 4; i < cv; i += 1024) {
        uint4 p = *reinterpret_cast<const uint4*>(binned + base + i);
        float v0 = bf2f(normh[p.x & SRC_MASK]);
        float v1 = bf2f(normh[p.y & SRC_MASK]);
        float v2 = bf2f(normh[p.z & SRC_MASK]);
        float v3 = bf2f(normh[p.w & SRC_MASK]);
        atomicAdd(&acc[p.x >> SRC_BITS], v0);
        atomicAdd(&acc[p.y >> SRC_BITS], v1);
        atomicAdd(&acc[p.z >> SRC_BITS], v2);
        atomicAdd(&acc[p.w >> SRC_BITS], v3);
    }
    for (int i = cv + tid; i < cnt; i += 256) {
        unsigned p = binned[base + i];
        atomicAdd(&acc[p >> SRC_BITS], bf2f(normh[p & SRC_MASK]));
    }
    __syncthreads();
    float bias2 = isb ? bf2f(((const bf16*)b2p)[0]) : ((const float*)b2p)[0];
    long node0 = (long)b * NPB;
    for (int i = tid; i < NPB; i += 256) {
        long node = node0 + i;
        if (node < N) {
            float di = dinv_v[node];
            float s2 = bf2f(normh[node]) + acc[i];
            dinv_v[node] = fmaf(di, s2, bias2);          // v, in place
        }
    }
}

// classifier: 8 images per block (proven round-2 structure), reads v directly
#define IMG 8
__global__ __launch_bounds__(256) void k_cls2(
    const float* __restrict__ vsrc,
    const void* __restrict__ Wlinp, const void* __restrict__ blinp,
    const void* __restrict__ Wclsp, const void* __restrict__ bclsp,
    void* __restrict__ outp, int B, long Ntot, const int* __restrict__ flag) {
    __shared__ __align__(16) float v[784 * IMG];   // v[k*IMG + img]
    __shared__ float z[IMG][128];
    __shared__ float lg[IMG * 10];
    int tid = threadIdx.x;
    int b0 = blockIdx.x * IMG;
    bool isb = (*flag) != 0;
    long base = (long)b0 * 784;

    for (int idx = tid; idx < 784 * IMG; idx += 256) {
        int img = idx / 784;
        int k = idx - img * 784;
        long node = base + (long)img * 784 + k;
        float val = 0.f;
        if (node < Ntot) val = vsrc[node];
        v[k * IMG + img] = val;
    }
    __syncthreads();

    int j = tid & 127;
    int half = tid >> 7;
    float bj = isb ? bf2f(((const bf16*)blinp)[j]) : ((const float*)blinp)[j];
    float a0 = bj, a1 = bj, a2 = bj, a3 = bj;
    const float4* v4 = reinterpret_cast<const float4*>(v);
    if (isb) {
        const bf16* Wlin = (const bf16*)Wlinp;
        #pragma unroll 4
        for (int k = 0; k < 784; ++k) {
            float w = bf2f(Wlin[k * 128 + j]);
            float4 vk = v4[k * 2 + half];
            a0 = fmaf(vk.x, w, a0); a1 = fmaf(vk.y, w, a1);
            a2 = fmaf(vk.z, w, a2); a3 = fmaf(vk.w, w, a3);
        }
    } else {
        const float* Wlin = (const float*)Wlinp;
        #pragma unroll 4
        for (int k = 0; k < 784; ++k) {
            float w = Wlin[k * 128 + j];
            float4 vk = v4[k * 2 + half];
            a0 = fmaf(vk.x, w, a0); a1 = fmaf(vk.y, w, a1);
            a2 = fmaf(vk.z, w, a2); a3 = fmaf(vk.w, w, a3);
        }
    }
    int ib = half * 4;
    z[ib + 0][j] = fmaxf(a0, 0.f);
    z[ib + 1][j] = fmaxf(a1, 0.f);
    z[ib + 2][j] = fmaxf(a2, 0.f);
    z[ib + 3][j] = fmaxf(a3, 0.f);
    __syncthreads();

    if (tid < IMG * 10) {
        int img = tid / 10, c = tid - img * 10;
        float l;
        if (isb) {
            const bf16* Wcls = (const bf16*)Wclsp;
            l = bf2f(((const bf16*)bclsp)[c]);
            #pragma unroll 8
            for (int jj = 0; jj < 128; ++jj) l = fmaf(z[img][jj], bf2f(Wcls[jj * 10 + c]), l);
        } else {
            const float* Wcls = (const float*)Wclsp;
            l = ((const float*)bclsp)[c];
            #pragma unroll 8
            for (int jj = 0; jj < 128; ++jj) l = fmaf(z[img][jj], Wcls[jj * 10 + c], l);
        }
        lg[tid] = l;
    }
    __syncthreads();

    if (tid < IMG && (b0 + tid) < B) {
        float m = -1e30f;
        #pragma unroll
        for (int c = 0; c < 10; ++c) m = fmaxf(m, lg[tid * 10 + c]);
        float se = 0.f;
        #pragma unroll
        for (int c = 0; c < 10; ++c) se += expf(lg[tid * 10 + c] - m);
        float lse = m + logf(se);
        long ob = (long)(b0 + tid) * 10;
        if (isb) {
            bf16* out = (bf16*)outp;
            #pragma unroll
            for (int c = 0; c < 10; ++c) out[ob + c] = __float2bfloat16(lg[tid * 10 + c] - lse);
        } else {
            float* out = (float*)outp;
            #pragma unroll
            for (int c = 0; c < 10; ++c) out[ob + c] = lg[tid * 10 + c] - lse;
        }
    }
}

// ======================= FALLBACK PATH (round-2, proven) =======================

__global__ void k_init(float* __restrict__ deg, int n) {
    int i = blockIdx.x * blockDim.x + threadIdx.x;
    if (i < n) deg[i] = 1.0f;
}

__global__ void k_node_a(float* __restrict__ deg_dinv, const void* __restrict__ xp,
                         bf16* __restrict__ normx, float* __restrict__ s1, int n,
                         const int* __restrict__ flag) {
    int i = blockIdx.x * blockDim.x + threadIdx.x;
    bool isb = (*flag) != 0;
    if (i < n) {
        float dg = deg_dinv[i];
        float di = rsqrtf(dg);
        float xv = isb ? bf2f(((const bf16*)xp)[i]) : ((const float*)xp)[i];
        float nx = di * xv;
        deg_dinv[i] = di;
        normx[i] = __float2bfloat16(nx);
        s1[i] = nx;
    }
}

__global__ void k_node_b(const float* __restrict__ dinv, bf16* __restrict__ normh,
                         float* __restrict__ s, const void* __restrict__ W1p,
                         const void* __restrict__ b1p, const void* __restrict__ W2p,
                         int n, const int* __restrict__ flag) {
    __shared__ float sh_ab[2];
    bool isb = (*flag) != 0;
    if (threadIdx.x == 0) {
        float a = 0.f, b = 0.f;
        if (isb) {
            const bf16* W1 = (const bf16*)W1p; const bf16* b1 = (const bf16*)b1p;
            const bf16* W2 = (const bf16*)W2p;
            #pragma unroll
            for (int k = 0; k < 16; ++k) {
                float w2 = bf2f(W2[k]);
                a += bf2f(W1[k]) * w2;
                b += bf2f(b1[k]) * w2;
            }
        } else {
            const float* W1 = (const float*)W1p; const float* b1 = (const float*)b1p;
            const float* W2 = (const float*)W2p;
            #pragma unroll
            for (int k = 0; k < 16; ++k) { a += W1[k] * W2[k]; b += b1[k] * W2[k]; }
        }
        sh_ab[0] = a; sh_ab[1] = b;
    }
    __syncthreads();
    float alpha = sh_ab[0], beta = sh_ab[1];
    int i = blockIdx.x * blockDim.x + threadIdx.x;
    if (i < n) {
        float di = dinv[i];
        float agg1 = di * s[i];
        float h2 = fmaf(alpha, agg1, beta);
        float nh = di * h2;
        normh[i] = __float2bfloat16(nh);
        s[i] = nh;
    }
}

template <bool VEC>
__global__ void k_count(const int* __restrict__ dst, float* __restrict__ deg, int E, int N) {
    int t = blockIdx.x * blockDim.x + threadIdx.x;
    int e0 = t * 4;
    if (VEC && (e0 + 3 < E)) {
        int4 d = *reinterpret_cast<const int4*>(dst + e0);
        if ((unsigned)d.x < (unsigned)N) atomicAdd(deg + d.x, 1.0f);
        if ((unsigned)d.y < (unsigned)N) atomicAdd(deg + d.y, 1.0f);
        if ((unsigned)d.z < (unsigned)N) atomicAdd(deg + d.z, 1.0f);
        if ((unsigned)d.w < (unsigned)N) atomicAdd(deg + d.w, 1.0f);
    } else {
        for (int e = e0; e < E && e < e0 + 4; ++e) {
            int d = dst[e];
            if ((unsigned)d < (unsigned)N) atomicAdd(deg + d, 1.0f);
        }
    }
}

template <bool VEC>
__global__ void k_scatter(const int* __restrict__ src, const int* __restrict__ dstp,
                          const bf16* __restrict__ val, float* __restrict__ acc,
                          int E, int N) {
    int t = blockIdx.x * blockDim.x + threadIdx.x;
    int e0 = t * 4;
    if (VEC && (e0 + 3 < E)) {
        int4 s = *reinterpret_cast<const int4*>(src + e0);
        int4 d = *reinterpret_cast<const int4*>(dstp + e0);
        float v0 = ((unsigned)s.x < (unsigned)N) ? bf2f(val[s.x]) : 0.f;
        float v1 = ((unsigned)s.y < (unsigned)N) ? bf2f(val[s.y]) : 0.f;
        float v2 = ((unsigned)s.z < (unsigned)N) ? bf2f(val[s.z]) : 0.f;
        float v3 = ((unsigned)s.w < (unsigned)N) ? bf2f(val[s.w]) : 0.f;
        if ((unsigned)d.x < (unsigned)N) atomicAdd(acc + d.x, v0);
        if ((unsigned)d.y < (unsigned)N) atomicAdd(acc + d.y, v1);
        if ((unsigned)d.z < (unsigned)N) atomicAdd(acc + d.z, v2);
        if ((unsigned)d.w < (unsigned)N) atomicAdd(acc + d.w, v3);
    } else {
        for (int e = e0; e < E && e < e0 + 4; ++e) {
            int sI = src[e], dI = dstp[e];
            if ((unsigned)sI < (unsigned)N && (unsigned)dI < (unsigned)N)
                atomicAdd(acc + dI, bf2f(val[sI]));
        }
    }
}

__global__ __launch_bounds__(256) void k_cls(
    const float* __restrict__ dinv, const float* __restrict__ s2,
    const void* __restrict__ b2p,
    const void* __restrict__ Wlinp, const void* __restrict__ blinp,
    const void* __restrict__ Wclsp, const void* __restrict__ bclsp,
    void* __restrict__ outp, int B, long Ntot, const int* __restrict__ flag) {
    __shared__ __align__(16) float v[784 * IMG];
    __shared__ float z[IMG][128];
    __shared__ float lg[IMG * 10];
    int tid = threadIdx.x;
    int b0 = blockIdx.x * IMG;
    bool isb = (*flag) != 0;
    float bias2 = isb ? bf2f(((const bf16*)b2p)[0]) : ((const float*)b2p)[0];
    long base = (long)b0 * 784;

    for (int idx = tid; idx < 784 * IMG; idx += 256) {
        int img = idx / 784;
        int k = idx - img * 784;
        long node = base + (long)img * 784 + k;
        float val = 0.f;
        if (node < Ntot) val = fmaf(dinv[node], s2[node], bias2);
        v[k * IMG + img] = val;
    }
    __syncthreads();

    int j = tid & 127;
    int half = tid >> 7;
    float bj = isb ? bf2f(((const bf16*)blinp)[j]) : ((const float*)blinp)[j];
    float a0 = bj, a1 = bj, a2 = bj, a3 = bj;
    const float4* v4 = reinterpret_cast<const float4*>(v);
    if (isb) {
        const bf16* Wlin = (const bf16*)Wlinp;
        #pragma unroll 4
        for (int k = 0; k < 784; ++k) {
            float w = bf2f(Wlin[k * 128 + j]);
            float4 vk = v4[k * 2 + half];
            a0 = fmaf(vk.x, w, a0); a1 = fmaf(vk.y, w, a1);
            a2 = fmaf(vk.z, w, a2); a3 = fmaf(vk.w, w, a3);
        }
    } else {
        const float* Wlin = (const float*)Wlinp;
        #pragma unroll 4
        for (int k = 0; k < 784; ++k) {
            float w = Wlin[k * 128 + j];
            float4 vk = v4[k * 2 + half];
            a0 = fmaf(vk.x, w, a0); a1 = fmaf(vk.y, w, a1);
            a2 = fmaf(vk.z, w, a2); a3 = fmaf(vk.w, w, a3);
        }
    }
    int ib = half * 4;
    z[ib + 0][j] = fmaxf(a0, 0.f);
    z[ib + 1][j] = fmaxf(a1, 0.f);
    z[ib + 2][j] = fmaxf(a2, 0.f);
    z[ib + 3][j] = fmaxf(a3, 0.f);
    __syncthreads();

    if (tid < IMG * 10) {
        int img = tid / 10, c = tid - img * 10;
        float l;
        if (isb) {
            const bf16* Wcls = (const bf16*)Wclsp;
            l = bf2f(((const bf16*)bclsp)[c]);
            #pragma unroll 8
            for (int jj = 0; jj < 128; ++jj) l = fmaf(z[img][jj], bf2f(Wcls[jj * 10 + c]), l);
        } else {
            const float* Wcls = (const float*)Wclsp;
            l = ((const float*)bclsp)[c];
            #pragma unroll 8
            for (int jj = 0; jj < 128; ++jj) l = fmaf(z[img][jj], Wcls[jj * 10 + c], l);
        }
        lg[tid] = l;
    }
    __syncthreads();

    if (tid < IMG && (b0 + tid) < B) {
        float m = -1e30f;
        #pragma unroll
        for (int c = 0; c < 10; ++c) m = fmaxf(m, lg[tid * 10 + c]);
        float se = 0.f;
        #pragma unroll
        for (int c = 0; c < 10; ++c) se += expf(lg[tid * 10 + c] - m);
        float lse = m + logf(se);
        long ob = (long)(b0 + tid) * 10;
        if (isb) {
            bf16* out = (bf16*)outp;
            #pragma unroll
            for (int c = 0; c < 10; ++c) out[ob + c] = __float2bfloat16(lg[tid * 10 + c] - lse);
        } else {
            float* out = (float*)outp;
            #pragma unroll
            for (int c = 0; c < 10; ++c) out[ob + c] = lg[tid * 10 + c] - lse;
        }
    }
}

// ======================= launcher =======================

extern "C" void kernel_launch(void* const* d_in, const int* in_sizes, int n_in,
                              void* d_out, int out_size, void* d_ws, size_t ws_size,
                              hipStream_t stream) {
    const void* x    = d_in[0];
    const int*  ei   = (const int*)d_in[1];
    const void* W1   = d_in[2];
    const void* b1   = d_in[3];
    const void* W2   = d_in[4];
    const void* b2   = d_in[5];
    const void* Wlin = d_in[6];
    const void* blin = d_in[7];
    const void* Wcls = d_in[8];
    const void* bcls = d_in[9];

    const int N = in_sizes[0];
    const int E = in_sizes[1] / 2;
    const int B = N / NPB;
    const int nb = (N + NPB - 1) / NPB;

    // exact counting-sort; cap = mean + 10% + 16, rounded down to mult of 4
    const long mean = (nb > 0) ? (long)E / nb : 0;
    const int cap = (int)((mean + mean / 10 + 16) & ~3L);

    const int* src = ei;
    const int* dst = ei + E;
    const bool vec = ((E & 3) == 0);
    const int eblk = ((E + 3) / 4 + 255) / 256;

    // fast-path workspace layout
    size_t off = 256;  // flag
    size_t cnt_off = off;  off += (size_t)nb * 4;        off = (off + 255) & ~255ull;
    size_t dinv_off = off; off += (size_t)N * 4;         off = (off + 255) & ~255ull;
    size_t nx_off = off;   off += (size_t)N * 2;         off = (off + 255) & ~255ull;
    size_t nh_off = off;   off += (size_t)N * 2;         off = (off + 255) & ~255ull;
    size_t hist_off = off; off += (size_t)BINBLK * nb * 4; off = (off + 255) & ~255ull;
    size_t bin_off = off;  off += (size_t)nb * (size_t)cap * 4;

    const bool cap_ok = (double)cap >= (double)mean + 8.0 * sqrt((double)(mean > 0 ? mean : 1));
    const bool fast = (N < (1 << SRC_BITS)) && (nb <= NB_MAX) && (ws_size >= off) && cap_ok;

    int* flag = (int*)d_ws;
    k_detect<<<1, 64, 0, stream>>>((const unsigned short*)x, flag);

    if (fast) {
        int*      counts = (int*)((char*)d_ws + cnt_off);
        float*    dinv   = (float*)((char*)d_ws + dinv_off);   // becomes v after k_agg2
        bf16*     normx  = (bf16*)((char*)d_ws + nx_off);
        bf16*     normh  = (bf16*)((char*)d_ws + nh_off);
        int*      hist   = (int*)((char*)d_ws + hist_off);
        unsigned* binned = (unsigned*)((char*)d_ws + bin_off);

        const int epb = (((E + BINBLK - 1) / BINBLK) + 3) & ~3;   // mult of 4

        if (vec) k_hist<true ><<<BINBLK, 1024, 0, stream>>>(dst, hist, E, N, nb, epb);
        else     k_hist<false><<<BINBLK, 1024, 0, stream>>>(dst, hist, E, N, nb, epb);
        k_scan<<<(nb + 3) / 4, 256, 0, stream>>>(hist, counts, nb, cap);
        if (vec) k_bin2<true ><<<BINBLK, 1024, 0, stream>>>(src, dst, binned, hist,
                                                            E, N, cap, nb, epb);
        else     k_bin2<false><<<BINBLK, 1024, 0, stream>>>(src, dst, binned, hist,
                                                            E, N, cap, nb, epb);
        k_deg <<<nb, 256, 0, stream>>>(binned, counts, x, dinv, normx, N, cap, flag);
        k_agg1<<<nb, 256, 0, stream>>>(binned, counts, dinv, normx, normh,
                                       W1, b1, W2, N, cap, flag);
        k_agg2<<<nb, 256, 0, stream>>>(binned, counts, dinv, normh, b2, N, cap, flag);
        k_cls2<<<(B + IMG - 1) / IMG, 256, 0, stream>>>(dinv, Wlin, blin, Wcls, bcls,
                                                        d_out, B, (long)N, flag);
    } else {
        float* buf0 = (float*)((char*)d_ws + 256);
        float* buf2 = buf0 + N;
        bf16*  buf1 = (bf16*)(buf2 + N);
        const int nblk = (N + 255) / 256;

        k_init<<<nblk, 256, 0, stream>>>(buf0, N);
        if (vec) k_count<true ><<<eblk, 256, 0, stream>>>(dst, buf0, E, N);
        else     k_count<false><<<eblk, 256, 0, stream>>>(dst, buf0, E, N);
        k_node_a<<<nblk, 256, 0, stream>>>(buf0, x, buf1, buf2, N, flag);
        if (vec) k_scatter<true ><<<eblk, 256, 0, stream>>>(src, dst, buf1, buf2, E, N);
        else     k_scatter<false><<<eblk, 256, 0, stream>>>(src, dst, buf1, buf2, E, N);
        k_node_b<<<nblk, 256, 0, stream>>>(buf0, buf1, buf2, W1, b1, W2, N, flag);
        if (vec) k_scatter<true ><<<eblk, 256, 0, stream>>>(src, dst, buf1, buf2, E, N);
        else     k_scatter<false><<<eblk, 256, 0, stream>>>(src, dst, buf1, buf2, E, N);
        k_cls<<<(B + IMG - 1) / IMG, 256, 0, stream>>>(buf0, buf2, b2, Wlin, blin,
                                                       Wcls, bcls, d_out, B, (long)N, flag);
    }
}

// Round 8
// 265.691 us; speedup vs baseline: 1.2297x; 1.2297x over previous
//
#include <hip/hip_runtime.h>
#include <hip/hip_bf16.h>
#include <math.h>

typedef __hip_bfloat16 bf16;

#define NPB 784                    // nodes per bucket == nodes per image
#define SRC_BITS 21
#define SRC_MASK ((1u << SRC_BITS) - 1u)
#define NB_MAX 2048                // max buckets the LDS kernels support
#define SCAP 16                    // staging slots per bucket (LDS)
#define SCAP_P 17                  // padded stride (bank-conflict break)
#define FCHUNK 8                   // flush granularity
#define BINBLK 256                 // blocks for hist/bin2 (scan assumes 256)

__device__ __forceinline__ float bf2f(bf16 v) { return __bfloat162float(v); }

// ---------- dtype detector ----------
__global__ void k_detect(const unsigned short* __restrict__ xr, int* __restrict__ flag) {
    if (blockIdx.x == 0 && threadIdx.x == 0) {
        int pl = 0;
        for (int i = 0; i < 64; ++i) {
            int e = (xr[i] >> 7) & 0xFF;
            if (e >= 110 && e <= 130) ++pl;
        }
        *flag = (pl >= 52) ? 1 : 0;
    }
}

// ======================= FAST PATH (counting-sort binning) =======================

// pass 1: per-(block,bucket) histogram of dst only. hist[block*nb + b].
template <bool VEC>
__global__ __launch_bounds__(1024) void k_hist(
    const int* __restrict__ dst, int* __restrict__ hist, int E, int N, int nb, int epb) {
    __shared__ int h[NB_MAX];
    int tid = threadIdx.x;
    for (int b = tid; b < nb; b += 1024) h[b] = 0;
    __syncthreads();
    int start = blockIdx.x * epb;
    int end = min(E, start + epb);
    for (int e0 = start + tid * 4; e0 < end; e0 += 4096) {
        if (VEC && (e0 + 3 < end)) {
            int4 d4 = *reinterpret_cast<const int4*>(dst + e0);
            if ((unsigned)d4.x < (unsigned)N) atomicAdd(&h[(unsigned)d4.x / (unsigned)NPB], 1);
            if ((unsigned)d4.y < (unsigned)N) atomicAdd(&h[(unsigned)d4.y / (unsigned)NPB], 1);
            if ((unsigned)d4.z < (unsigned)N) atomicAdd(&h[(unsigned)d4.z / (unsigned)NPB], 1);
            if ((unsigned)d4.w < (unsigned)N) atomicAdd(&h[(unsigned)d4.w / (unsigned)NPB], 1);
        } else {
            for (int e = e0; e < end && e < e0 + 4; ++e) {
                unsigned du = (unsigned)dst[e];
                if (du < (unsigned)N) atomicAdd(&h[du / (unsigned)NPB], 1);
            }
        }
    }
    __syncthreads();
    int* hrow = hist + (size_t)blockIdx.x * nb;
    for (int b = tid; b < nb; b += 1024) hrow[b] = h[b];
}

// scan: one wave per bucket; prefix over 256 block counts (in place).
__global__ __launch_bounds__(256) void k_scan(
    int* __restrict__ hist, int* __restrict__ counts, int nb, int cap) {
    int wid = blockIdx.x * 4 + (threadIdx.x >> 6);   // bucket id
    int lane = threadIdx.x & 63;
    if (wid >= nb) return;
    int v0 = hist[(size_t)(lane * 4 + 0) * nb + wid];
    int v1 = hist[(size_t)(lane * 4 + 1) * nb + wid];
    int v2 = hist[(size_t)(lane * 4 + 2) * nb + wid];
    int v3 = hist[(size_t)(lane * 4 + 3) * nb + wid];
    int s = v0 + v1 + v2 + v3;
    int e = s;
    #pragma unroll
    for (int off = 1; off < 64; off <<= 1) {
        int t = __shfl_up(e, off, 64);
        if (lane >= off) e += t;
    }
    int total = __shfl(e, 63, 64);
    e -= s;                                           // exclusive prefix
    int p = wid * cap + e;
    hist[(size_t)(lane * 4 + 0) * nb + wid] = p; p += v0;
    hist[(size_t)(lane * 4 + 1) * nb + wid] = p; p += v1;
    hist[(size_t)(lane * 4 + 2) * nb + wid] = p; p += v2;
    hist[(size_t)(lane * 4 + 3) * nb + wid] = p;
    if (lane == 0) counts[wid] = total;
}

// pass 2: place edges; cursors in LDS (pre-reserved exact regions).
__device__ __forceinline__ void bin_one2(int dd, int ss, int N,
                                         unsigned* stage, int* lcnt, int* lcur,
                                         unsigned* __restrict__ binned, int cap) {
    unsigned du = (unsigned)dd;
    if (du < (unsigned)N) {
        unsigned su = (unsigned)ss;
        if (su >= (unsigned)N) su = (unsigned)(N - 1);   // defensive clamp
        unsigned b  = du / (unsigned)NPB;
        unsigned lo = du - b * (unsigned)NPB;
        unsigned pk = (lo << SRC_BITS) | su;
        int idx = atomicAdd(&lcnt[b], 1);
        if (idx < SCAP) {
            stage[b * SCAP_P + idx] = pk;
        } else {                      // rare in-batch overflow: direct place
            int pos = atomicAdd(&lcur[b], 1);
            if (pos < (int)((b + 1) * (unsigned)cap)) binned[pos] = pk;
        }
    }
}

__device__ __forceinline__ void bin_flush2(unsigned* stage, int* lcnt, int* lcur,
                                           unsigned* __restrict__ binned,
                                           int nb, int cap, bool drain, int tid) {
    for (int b = tid; b < nb; b += 1024) {
        int c = lcnt[b];
        int valid = c < SCAP ? c : SCAP;
        int cntf = drain ? valid : (valid & ~(FCHUNK - 1));
        if (cntf > 0) {
            int pos = atomicAdd(&lcur[b], cntf);
            int lim = (b + 1) * cap;
            unsigned* s = stage + b * SCAP_P;
            int k = 0;
            if (pos + cntf <= lim) {
                int head = (4 - (pos & 3)) & 3;
                if (head > cntf) head = cntf;
                for (; k < head; ++k) binned[pos + k] = s[k];
                for (; k + 4 <= cntf; k += 4) {
                    uint4 v; v.x = s[k]; v.y = s[k + 1]; v.z = s[k + 2]; v.w = s[k + 3];
                    *reinterpret_cast<uint4*>(binned + pos + k) = v;
                }
                for (; k < cntf; ++k) binned[pos + k] = s[k];
            } else {
                for (; k < cntf; ++k)
                    if (pos + k < lim) binned[pos + k] = s[k];
            }
            int rem = valid - cntf;
            for (int kk = 0; kk < rem; ++kk) s[kk] = s[cntf + kk];
            lcnt[b] = rem;
        }
    }
}

template <bool VEC>
__global__ __launch_bounds__(1024) void k_bin2(
    const int* __restrict__ src, const int* __restrict__ dst,
    unsigned* __restrict__ binned, const int* __restrict__ offs,
    int E, int N, int cap, int nb, int epb) {
    __shared__ unsigned stage[NB_MAX * SCAP_P];   // 136 KB (padded)
    __shared__ int lcnt[NB_MAX];                  // 8 KB
    __shared__ int lcur[NB_MAX];                  // 8 KB
    int tid = threadIdx.x;
    const int* orow = offs + (size_t)blockIdx.x * nb;
    for (int b = tid; b < nb; b += 1024) { lcnt[b] = 0; lcur[b] = orow[b]; }
    __syncthreads();
    int start = blockIdx.x * epb;
    int end = min(E, start + epb);
    if (start >= end) return;   // uniform across block

    int e_cur = start + tid * 4;
    int4 s_cur, d_cur;
    bool v_cur = VEC && (e_cur + 3 < end);
    if (v_cur) {
        s_cur = *reinterpret_cast<const int4*>(src + e_cur);
        d_cur = *reinterpret_cast<const int4*>(dst + e_cur);
    }
    for (int base_e = start; base_e < end; base_e += 4096) {
        int e_nxt = e_cur + 4096;
        int4 s_nxt, d_nxt;
        bool v_nxt = VEC && (base_e + 4096 < end) && (e_nxt + 3 < end);
        if (v_nxt) {
            s_nxt = *reinterpret_cast<const int4*>(src + e_nxt);
            d_nxt = *reinterpret_cast<const int4*>(dst + e_nxt);
        }
        if (e_cur < end) {
            if (v_cur) {
                bin_one2(d_cur.x, s_cur.x, N, stage, lcnt, lcur, binned, cap);
                bin_one2(d_cur.y, s_cur.y, N, stage, lcnt, lcur, binned, cap);
                bin_one2(d_cur.z, s_cur.z, N, stage, lcnt, lcur, binned, cap);
                bin_one2(d_cur.w, s_cur.w, N, stage, lcnt, lcur, binned, cap);
            } else {
                for (int e = e_cur; e < end && e < e_cur + 4; ++e)
                    bin_one2(dst[e], src[e], N, stage, lcnt, lcur, binned, cap);
            }
        }
        __syncthreads();
        bool last = (base_e + 4096 >= end);
        bin_flush2(stage, lcnt, lcur, binned, nb, cap, last, tid);
        __syncthreads();
        e_cur = e_nxt; s_cur = s_nxt; d_cur = d_nxt; v_cur = v_nxt;
    }
}

// ---------- consumers (one block per bucket) ----------

__global__ __launch_bounds__(256) void k_deg(
    const unsigned* __restrict__ binned, const int* __restrict__ counts,
    const void* __restrict__ xp, float* __restrict__ dinv, bf16* __restrict__ normx,
    int N, int cap, const int* __restrict__ flag) {
    __shared__ int ideg[NPB];
    int b = blockIdx.x, tid = threadIdx.x;
    for (int i = tid; i < NPB; i += 256) ideg[i] = 1;   // self-loop
    __syncthreads();
    int base = b * cap;
    int cnt = min(counts[b], cap);
    int cv = cnt & ~3;
    for (int i = tid * 4; i < cv; i += 1024) {
        uint4 p = *reinterpret_cast<const uint4*>(binned + base + i);
        atomicAdd(&ideg[p.x >> SRC_BITS], 1);
        atomicAdd(&ideg[p.y >> SRC_BITS], 1);
        atomicAdd(&ideg[p.z >> SRC_BITS], 1);
        atomicAdd(&ideg[p.w >> SRC_BITS], 1);
    }
    for (int i = cv + tid; i < cnt; i += 256)
        atomicAdd(&ideg[binned[base + i] >> SRC_BITS], 1);
    __syncthreads();
    bool isb = (*flag) != 0;
    long node0 = (long)b * NPB;
    for (int i = tid; i < NPB; i += 256) {
        long node = node0 + i;
        if (node < N) {
            float di = rsqrtf((float)ideg[i]);
            float xv = isb ? bf2f(((const bf16*)xp)[node]) : ((const float*)xp)[node];
            dinv[node] = di;
            normx[node] = __float2bfloat16(di * xv);
        }
    }
}

__global__ __launch_bounds__(256) void k_agg1(
    const unsigned* __restrict__ binned, const int* __restrict__ counts,
    const float* __restrict__ dinv, const bf16* __restrict__ normx,
    bf16* __restrict__ normh,
    const void* __restrict__ W1p, const void* __restrict__ b1p,
    const void* __restrict__ W2p, int N, int cap, const int* __restrict__ flag) {
    __shared__ float acc[NPB];
    __shared__ float sh_ab[2];
    int b = blockIdx.x, tid = threadIdx.x;
    bool isb = (*flag) != 0;
    if (tid == 0) {
        float a = 0.f, bb = 0.f;
        if (isb) {
            const bf16* W1 = (const bf16*)W1p; const bf16* b1 = (const bf16*)b1p;
            const bf16* W2 = (const bf16*)W2p;
            #pragma unroll
            for (int k = 0; k < 16; ++k) {
                float w2 = bf2f(W2[k]);
                a += bf2f(W1[k]) * w2;
                bb += bf2f(b1[k]) * w2;
            }
        } else {
            const float* W1 = (const float*)W1p; const float* b1 = (const float*)b1p;
            const float* W2 = (const float*)W2p;
            #pragma unroll
            for (int k = 0; k < 16; ++k) { a += W1[k] * W2[k]; bb += b1[k] * W2[k]; }
        }
        sh_ab[0] = a; sh_ab[1] = bb;
    }
    for (int i = tid; i < NPB; i += 256) acc[i] = 0.f;
    __syncthreads();
    int base = b * cap;
    int cnt = min(counts[b], cap);
    int cv = cnt & ~3;
    for (int i = tid * 4; i < cv; i += 1024) {
        uint4 p = *reinterpret_cast<const uint4*>(binned + base + i);
        float v0 = bf2f(normx[p.x & SRC_MASK]);
        float v1 = bf2f(normx[p.y & SRC_MASK]);
        float v2 = bf2f(normx[p.z & SRC_MASK]);
        float v3 = bf2f(normx[p.w & SRC_MASK]);
        atomicAdd(&acc[p.x >> SRC_BITS], v0);
        atomicAdd(&acc[p.y >> SRC_BITS], v1);
        atomicAdd(&acc[p.z >> SRC_BITS], v2);
        atomicAdd(&acc[p.w >> SRC_BITS], v3);
    }
    for (int i = cv + tid; i < cnt; i += 256) {
        unsigned p = binned[base + i];
        atomicAdd(&acc[p >> SRC_BITS], bf2f(normx[p & SRC_MASK]));
    }
    __syncthreads();
    float alpha = sh_ab[0], beta = sh_ab[1];
    long node0 = (long)b * NPB;
    for (int i = tid; i < NPB; i += 256) {
        long node = node0 + i;
        if (node < N) {
            float di = dinv[node];
            float s1 = bf2f(normx[node]) + acc[i];       // self + neighbors
            float h2 = fmaf(alpha, di * s1, beta);       // layer-2 pre-act
            normh[node] = __float2bfloat16(di * h2);
        }
    }
}

// layer-2 aggregation + fused classifier with j-vectorized GEMV (1 image/block)
__global__ __launch_bounds__(256) void k_agg2c(
    const unsigned* __restrict__ binned, const int* __restrict__ counts,
    const float* __restrict__ dinv, const bf16* __restrict__ normh,
    const void* __restrict__ b2p,
    const void* __restrict__ Wlinp, const void* __restrict__ blinp,
    const void* __restrict__ Wclsp, const void* __restrict__ bclsp,
    void* __restrict__ outp, int N, int cap, int B, const int* __restrict__ flag) {
    __shared__ float acc[NPB];          // neighbor sums -> v
    __shared__ float zpart[16][128];    // k-group partials
    __shared__ float z[128];
    __shared__ float lg[10];
    int b = blockIdx.x, tid = threadIdx.x;
    bool isb = (*flag) != 0;
    for (int i = tid; i < NPB; i += 256) acc[i] = 0.f;
    __syncthreads();
    int base = b * cap;
    int cnt = min(counts[b], cap);
    int cv = cnt & ~3;
    for (int i = tid * 4; i < cv; i += 1024) {
        uint4 p = *reinterpret_cast<const uint4*>(binned + base + i);
        float v0 = bf2f(normh[p.x & SRC_MASK]);
        float v1 = bf2f(normh[p.y & SRC_MASK]);
        float v2 = bf2f(normh[p.z & SRC_MASK]);
        float v3 = bf2f(normh[p.w & SRC_MASK]);
        atomicAdd(&acc[p.x >> SRC_BITS], v0);
        atomicAdd(&acc[p.y >> SRC_BITS], v1);
        atomicAdd(&acc[p.z >> SRC_BITS], v2);
        atomicAdd(&acc[p.w >> SRC_BITS], v3);
    }
    for (int i = cv + tid; i < cnt; i += 256) {
        unsigned p = binned[base + i];
        atomicAdd(&acc[p >> SRC_BITS], bf2f(normh[p & SRC_MASK]));
    }
    __syncthreads();
    float bias2 = isb ? bf2f(((const bf16*)b2p)[0]) : ((const float*)b2p)[0];
    long node0 = (long)b * NPB;
    for (int i = tid; i < NPB; i += 256) {
        long node = node0 + i;
        float vv = 0.f;
        if (node < N) {
            float di = dinv[node];
            float s2 = bf2f(normh[node]) + acc[i];
            vv = fmaf(di, s2, bias2);                    // v = agg2 + b2
        }
        acc[i] = vv;
    }
    __syncthreads();
    // GEMV 784->128: 16 j-groups (8 consecutive j, 16B W loads) x 16 k-groups (49 k)
    {
        int jg = tid & 15, kg = tid >> 4;
        int j8 = jg * 8;
        float p0 = 0.f, p1 = 0.f, p2 = 0.f, p3 = 0.f;
        float p4 = 0.f, p5 = 0.f, p6 = 0.f, p7 = 0.f;
        int k0 = kg * 49, k1 = k0 + 49;
        if (isb) {
            const bf16* W = (const bf16*)Wlinp;
            for (int k = k0; k < k1; ++k) {
                uint4 u = *reinterpret_cast<const uint4*>(W + (size_t)k * 128 + j8);
                float vk = acc[k];
                p0 = fmaf(vk, __uint_as_float(u.x << 16), p0);
                p1 = fmaf(vk, __uint_as_float(u.x & 0xFFFF0000u), p1);
                p2 = fmaf(vk, __uint_as_float(u.y << 16), p2);
                p3 = fmaf(vk, __uint_as_float(u.y & 0xFFFF0000u), p3);
                p4 = fmaf(vk, __uint_as_float(u.z << 16), p4);
                p5 = fmaf(vk, __uint_as_float(u.z & 0xFFFF0000u), p5);
                p6 = fmaf(vk, __uint_as_float(u.w << 16), p6);
                p7 = fmaf(vk, __uint_as_float(u.w & 0xFFFF0000u), p7);
            }
        } else {
            const float* W = (const float*)Wlinp;
            for (int k = k0; k < k1; ++k) {
                float4 wa = *reinterpret_cast<const float4*>(W + (size_t)k * 128 + j8);
                float4 wb = *reinterpret_cast<const float4*>(W + (size_t)k * 128 + j8 + 4);
                float vk = acc[k];
                p0 = fmaf(vk, wa.x, p0); p1 = fmaf(vk, wa.y, p1);
                p2 = fmaf(vk, wa.z, p2); p3 = fmaf(vk, wa.w, p3);
                p4 = fmaf(vk, wb.x, p4); p5 = fmaf(vk, wb.y, p5);
                p6 = fmaf(vk, wb.z, p6); p7 = fmaf(vk, wb.w, p7);
            }
        }
        zpart[kg][j8 + 0] = p0; zpart[kg][j8 + 1] = p1;
        zpart[kg][j8 + 2] = p2; zpart[kg][j8 + 3] = p3;
        zpart[kg][j8 + 4] = p4; zpart[kg][j8 + 5] = p5;
        zpart[kg][j8 + 6] = p6; zpart[kg][j8 + 7] = p7;
    }
    __syncthreads();
    if (tid < 128) {
        float s = isb ? bf2f(((const bf16*)blinp)[tid]) : ((const float*)blinp)[tid];
        #pragma unroll
        for (int kg = 0; kg < 16; ++kg) s += zpart[kg][tid];
        z[tid] = fmaxf(s, 0.f);
    }
    __syncthreads();
    if (tid < 10) {
        float l = isb ? bf2f(((const bf16*)bclsp)[tid]) : ((const float*)bclsp)[tid];
        if (isb) {
            const bf16* W = (const bf16*)Wclsp;
            #pragma unroll 8
            for (int jj = 0; jj < 128; ++jj) l = fmaf(z[jj], bf2f(W[jj * 10 + tid]), l);
        } else {
            const float* W = (const float*)Wclsp;
            #pragma unroll 8
            for (int jj = 0; jj < 128; ++jj) l = fmaf(z[jj], W[jj * 10 + tid], l);
        }
        lg[tid] = l;
    }
    __syncthreads();
    if (tid == 0 && b < B) {
        float m = -1e30f;
        #pragma unroll
        for (int c = 0; c < 10; ++c) m = fmaxf(m, lg[c]);
        float se = 0.f;
        #pragma unroll
        for (int c = 0; c < 10; ++c) se += expf(lg[c] - m);
        float lse = m + logf(se);
        long ob = (long)b * 10;
        if (isb) {
            bf16* o = (bf16*)outp;
            #pragma unroll
            for (int c = 0; c < 10; ++c) o[ob + c] = __float2bfloat16(lg[c] - lse);
        } else {
            float* o = (float*)outp;
            #pragma unroll
            for (int c = 0; c < 10; ++c) o[ob + c] = lg[c] - lse;
        }
    }
}

// ======================= FALLBACK PATH (round-2, proven) =======================

__global__ void k_init(float* __restrict__ deg, int n) {
    int i = blockIdx.x * blockDim.x + threadIdx.x;
    if (i < n) deg[i] = 1.0f;
}

__global__ void k_node_a(float* __restrict__ deg_dinv, const void* __restrict__ xp,
                         bf16* __restrict__ normx, float* __restrict__ s1, int n,
                         const int* __restrict__ flag) {
    int i = blockIdx.x * blockDim.x + threadIdx.x;
    bool isb = (*flag) != 0;
    if (i < n) {
        float dg = deg_dinv[i];
        float di = rsqrtf(dg);
        float xv = isb ? bf2f(((const bf16*)xp)[i]) : ((const float*)xp)[i];
        float nx = di * xv;
        deg_dinv[i] = di;
        normx[i] = __float2bfloat16(nx);
        s1[i] = nx;
    }
}

__global__ void k_node_b(const float* __restrict__ dinv, bf16* __restrict__ normh,
                         float* __restrict__ s, const void* __restrict__ W1p,
                         const void* __restrict__ b1p, const void* __restrict__ W2p,
                         int n, const int* __restrict__ flag) {
    __shared__ float sh_ab[2];
    bool isb = (*flag) != 0;
    if (threadIdx.x == 0) {
        float a = 0.f, b = 0.f;
        if (isb) {
            const bf16* W1 = (const bf16*)W1p; const bf16* b1 = (const bf16*)b1p;
            const bf16* W2 = (const bf16*)W2p;
            #pragma unroll
            for (int k = 0; k < 16; ++k) {
                float w2 = bf2f(W2[k]);
                a += bf2f(W1[k]) * w2;
                b += bf2f(b1[k]) * w2;
            }
        } else {
            const float* W1 = (const float*)W1p; const float* b1 = (const float*)b1p;
            const float* W2 = (const float*)W2p;
            #pragma unroll
            for (int k = 0; k < 16; ++k) { a += W1[k] * W2[k]; b += b1[k] * W2[k]; }
        }
        sh_ab[0] = a; sh_ab[1] = b;
    }
    __syncthreads();
    float alpha = sh_ab[0], beta = sh_ab[1];
    int i = blockIdx.x * blockDim.x + threadIdx.x;
    if (i < n) {
        float di = dinv[i];
        float agg1 = di * s[i];
        float h2 = fmaf(alpha, agg1, beta);
        float nh = di * h2;
        normh[i] = __float2bfloat16(nh);
        s[i] = nh;
    }
}

template <bool VEC>
__global__ void k_count(const int* __restrict__ dst, float* __restrict__ deg, int E, int N) {
    int t = blockIdx.x * blockDim.x + threadIdx.x;
    int e0 = t * 4;
    if (VEC && (e0 + 3 < E)) {
        int4 d = *reinterpret_cast<const int4*>(dst + e0);
        if ((unsigned)d.x < (unsigned)N) atomicAdd(deg + d.x, 1.0f);
        if ((unsigned)d.y < (unsigned)N) atomicAdd(deg + d.y, 1.0f);
        if ((unsigned)d.z < (unsigned)N) atomicAdd(deg + d.z, 1.0f);
        if ((unsigned)d.w < (unsigned)N) atomicAdd(deg + d.w, 1.0f);
    } else {
        for (int e = e0; e < E && e < e0 + 4; ++e) {
            int d = dst[e];
            if ((unsigned)d < (unsigned)N) atomicAdd(deg + d, 1.0f);
        }
    }
}

template <bool VEC>
__global__ void k_scatter(const int* __restrict__ src, const int* __restrict__ dstp,
                          const bf16* __restrict__ val, float* __restrict__ acc,
                          int E, int N) {
    int t = blockIdx.x * blockDim.x + threadIdx.x;
    int e0 = t * 4;
    if (VEC && (e0 + 3 < E)) {
        int4 s = *reinterpret_cast<const int4*>(src + e0);
        int4 d = *reinterpret_cast<const int4*>(dstp + e0);
        float v0 = ((unsigned)s.x < (unsigned)N) ? bf2f(val[s.x]) : 0.f;
        float v1 = ((unsigned)s.y < (unsigned)N) ? bf2f(val[s.y]) : 0.f;
        float v2 = ((unsigned)s.z < (unsigned)N) ? bf2f(val[s.z]) : 0.f;
        float v3 = ((unsigned)s.w < (unsigned)N) ? bf2f(val[s.w]) : 0.f;
        if ((unsigned)d.x < (unsigned)N) atomicAdd(acc + d.x, v0);
        if ((unsigned)d.y < (unsigned)N) atomicAdd(acc + d.y, v1);
        if ((unsigned)d.z < (unsigned)N) atomicAdd(acc + d.z, v2);
        if ((unsigned)d.w < (unsigned)N) atomicAdd(acc + d.w, v3);
    } else {
        for (int e = e0; e < E && e < e0 + 4; ++e) {
            int sI = src[e], dI = dstp[e];
            if ((unsigned)sI < (unsigned)N && (unsigned)dI < (unsigned)N)
                atomicAdd(acc + dI, bf2f(val[sI]));
        }
    }
}

#define IMG 8
__global__ __launch_bounds__(256) void k_cls(
    const float* __restrict__ dinv, const float* __restrict__ s2,
    const void* __restrict__ b2p,
    const void* __restrict__ Wlinp, const void* __restrict__ blinp,
    const void* __restrict__ Wclsp, const void* __restrict__ bclsp,
    void* __restrict__ outp, int B, long Ntot, const int* __restrict__ flag) {
    __shared__ __align__(16) float v[784 * IMG];
    __shared__ float z[IMG][128];
    __shared__ float lg[IMG * 10];
    int tid = threadIdx.x;
    int b0 = blockIdx.x * IMG;
    bool isb = (*flag) != 0;
    float bias2 = isb ? bf2f(((const bf16*)b2p)[0]) : ((const float*)b2p)[0];
    long base = (long)b0 * 784;

    for (int idx = tid; idx < 784 * IMG; idx += 256) {
        int img = idx / 784;
        int k = idx - img * 784;
        long node = base + (long)img * 784 + k;
        float val = 0.f;
        if (node < Ntot) val = fmaf(dinv[node], s2[node], bias2);
        v[k * IMG + img] = val;
    }
    __syncthreads();

    int j = tid & 127;
    int half = tid >> 7;
    float bj = isb ? bf2f(((const bf16*)blinp)[j]) : ((const float*)blinp)[j];
    float a0 = bj, a1 = bj, a2 = bj, a3 = bj;
    const float4* v4 = reinterpret_cast<const float4*>(v);
    if (isb) {
        const bf16* Wlin = (const bf16*)Wlinp;
        #pragma unroll 4
        for (int k = 0; k < 784; ++k) {
            float w = bf2f(Wlin[k * 128 + j]);
            float4 vk = v4[k * 2 + half];
            a0 = fmaf(vk.x, w, a0); a1 = fmaf(vk.y, w, a1);
            a2 = fmaf(vk.z, w, a2); a3 = fmaf(vk.w, w, a3);
        }
    } else {
        const float* Wlin = (const float*)Wlinp;
        #pragma unroll 4
        for (int k = 0; k < 784; ++k) {
            float w = Wlin[k * 128 + j];
            float4 vk = v4[k * 2 + half];
            a0 = fmaf(vk.x, w, a0); a1 = fmaf(vk.y, w, a1);
            a2 = fmaf(vk.z, w, a2); a3 = fmaf(vk.w, w, a3);
        }
    }
    int ib = half * 4;
    z[ib + 0][j] = fmaxf(a0, 0.f);
    z[ib + 1][j] = fmaxf(a1, 0.f);
    z[ib + 2][j] = fmaxf(a2, 0.f);
    z[ib + 3][j] = fmaxf(a3, 0.f);
    __syncthreads();

    if (tid < IMG * 10) {
        int img = tid / 10, c = tid - img * 10;
        float l;
        if (isb) {
            const bf16* Wcls = (const bf16*)Wclsp;
            l = bf2f(((const bf16*)bclsp)[c]);
            #pragma unroll 8
            for (int jj = 0; jj < 128; ++jj) l = fmaf(z[img][jj], bf2f(Wcls[jj * 10 + c]), l);
        } else {
            const float* Wcls = (const float*)Wclsp;
            l = ((const float*)bclsp)[c];
            #pragma unroll 8
            for (int jj = 0; jj < 128; ++jj) l = fmaf(z[img][jj], Wcls[jj * 10 + c], l);
        }
        lg[tid] = l;
    }
    __syncthreads();

    if (tid < IMG && (b0 + tid) < B) {
        float m = -1e30f;
        #pragma unroll
        for (int c = 0; c < 10; ++c) m = fmaxf(m, lg[tid * 10 + c]);
        float se = 0.f;
        #pragma unroll
        for (int c = 0; c < 10; ++c) se += expf(lg[tid * 10 + c] - m);
        float lse = m + logf(se);
        long ob = (long)(b0 + tid) * 10;
        if (isb) {
            bf16* out = (bf16*)outp;
            #pragma unroll
            for (int c = 0; c < 10; ++c) out[ob + c] = __float2bfloat16(lg[tid * 10 + c] - lse);
        } else {
            float* out = (float*)outp;
            #pragma unroll
            for (int c = 0; c < 10; ++c) out[ob + c] = lg[tid * 10 + c] - lse;
        }
    }
}

// ======================= launcher =======================

extern "C" void kernel_launch(void* const* d_in, const int* in_sizes, int n_in,
                              void* d_out, int out_size, void* d_ws, size_t ws_size,
                              hipStream_t stream) {
    const void* x    = d_in[0];
    const int*  ei   = (const int*)d_in[1];
    const void* W1   = d_in[2];
    const void* b1   = d_in[3];
    const void* W2   = d_in[4];
    const void* b2   = d_in[5];
    const void* Wlin = d_in[6];
    const void* blin = d_in[7];
    const void* Wcls = d_in[8];
    const void* bcls = d_in[9];

    const int N = in_sizes[0];
    const int E = in_sizes[1] / 2;
    const int B = N / NPB;
    const int nb = (N + NPB - 1) / NPB;

    // exact counting-sort; cap = mean + 10% + 16, rounded down to mult of 4
    const long mean = (nb > 0) ? (long)E / nb : 0;
    const int cap = (int)((mean + mean / 10 + 16) & ~3L);

    const int* src = ei;
    const int* dst = ei + E;
    const bool vec = ((E & 3) == 0);
    const int eblk = ((E + 3) / 4 + 255) / 256;

    // fast-path workspace layout
    size_t off = 256;  // flag
    size_t cnt_off = off;  off += (size_t)nb * 4;        off = (off + 255) & ~255ull;
    size_t dinv_off = off; off += (size_t)N * 4;         off = (off + 255) & ~255ull;
    size_t nx_off = off;   off += (size_t)N * 2;         off = (off + 255) & ~255ull;
    size_t nh_off = off;   off += (size_t)N * 2;         off = (off + 255) & ~255ull;
    size_t hist_off = off; off += (size_t)BINBLK * nb * 4; off = (off + 255) & ~255ull;
    size_t bin_off = off;  off += (size_t)nb * (size_t)cap * 4;

    const bool cap_ok = (double)cap >= (double)mean + 8.0 * sqrt((double)(mean > 0 ? mean : 1));
    const bool fast = (N < (1 << SRC_BITS)) && (nb <= NB_MAX) && (ws_size >= off) && cap_ok;

    int* flag = (int*)d_ws;
    k_detect<<<1, 64, 0, stream>>>((const unsigned short*)x, flag);

    if (fast) {
        int*      counts = (int*)((char*)d_ws + cnt_off);
        float*    dinv   = (float*)((char*)d_ws + dinv_off);
        bf16*     normx  = (bf16*)((char*)d_ws + nx_off);
        bf16*     normh  = (bf16*)((char*)d_ws + nh_off);
        int*      hist   = (int*)((char*)d_ws + hist_off);
        unsigned* binned = (unsigned*)((char*)d_ws + bin_off);

        const int epb = (((E + BINBLK - 1) / BINBLK) + 3) & ~3;   // mult of 4

        if (vec) k_hist<true ><<<BINBLK, 1024, 0, stream>>>(dst, hist, E, N, nb, epb);
        else     k_hist<false><<<BINBLK, 1024, 0, stream>>>(dst, hist, E, N, nb, epb);
        k_scan<<<(nb + 3) / 4, 256, 0, stream>>>(hist, counts, nb, cap);
        if (vec) k_bin2<true ><<<BINBLK, 1024, 0, stream>>>(src, dst, binned, hist,
                                                            E, N, cap, nb, epb);
        else     k_bin2<false><<<BINBLK, 1024, 0, stream>>>(src, dst, binned, hist,
                                                            E, N, cap, nb, epb);
        k_deg <<<nb, 256, 0, stream>>>(binned, counts, x, dinv, normx, N, cap, flag);
        k_agg1<<<nb, 256, 0, stream>>>(binned, counts, dinv, normx, normh,
                                       W1, b1, W2, N, cap, flag);
        k_agg2c<<<nb, 256, 0, stream>>>(binned, counts, dinv, normh, b2,
                                        Wlin, blin, Wcls, bcls, d_out, N, cap, B, flag);
    } else {
        float* buf0 = (float*)((char*)d_ws + 256);
        float* buf2 = buf0 + N;
        bf16*  buf1 = (bf16*)(buf2 + N);
        const int nblk = (N + 255) / 256;

        k_init<<<nblk, 256, 0, stream>>>(buf0, N);
        if (vec) k_count<true ><<<eblk, 256, 0, stream>>>(dst, buf0, E, N);
        else     k_count<false><<<eblk, 256, 0, stream>>>(dst, buf0, E, N);
        k_node_a<<<nblk, 256, 0, stream>>>(buf0, x, buf1, buf2, N, flag);
        if (vec) k_scatter<true ><<<eblk, 256, 0, stream>>>(src, dst, buf1, buf2, E, N);
        else     k_scatter<false><<<eblk, 256, 0, stream>>>(src, dst, buf1, buf2, E, N);
        k_node_b<<<nblk, 256, 0, stream>>>(buf0, buf1, buf2, W1, b1, W2, N, flag);
        if (vec) k_scatter<true ><<<eblk, 256, 0, stream>>>(src, dst, buf1, buf2, E, N);
        else     k_scatter<false><<<eblk, 256, 0, stream>>>(src, dst, buf1, buf2, E, N);
        k_cls<<<(B + IMG - 1) / IMG, 256, 0, stream>>>(buf0, buf2, b2, Wlin, blin,
                                                       Wcls, bcls, d_out, B, (long)N, flag);
    }
}

// Round 9
// 265.183 us; speedup vs baseline: 1.2320x; 1.0019x over previous
//
#include <hip/hip_runtime.h>
#include <hip/hip_bf16.h>
#include <math.h>

typedef __hip_bfloat16 bf16;

#define NPB 784                    // nodes per bucket == nodes per image
#define SRC_BITS 21
#define SRC_MASK ((1u << SRC_BITS) - 1u)
#define NB_MAX 2048                // max buckets the LDS kernels support
#define SCAP 16                    // staging slots per bucket (LDS)
#define SCAP_P 17                  // padded stride (bank-conflict break)
#define FCHUNK 8                   // flush granularity
#define BINBLK 256                 // blocks for hist/bin2 (scan assumes 256)

__device__ __forceinline__ float bf2f(bf16 v) { return __bfloat162float(v); }

// ---------- dtype detector ----------
__global__ void k_detect(const unsigned short* __restrict__ xr, int* __restrict__ flag) {
    if (blockIdx.x == 0 && threadIdx.x == 0) {
        int pl = 0;
        for (int i = 0; i < 64; ++i) {
            int e = (xr[i] >> 7) & 0xFF;
            if (e >= 110 && e <= 130) ++pl;
        }
        *flag = (pl >= 52) ? 1 : 0;
    }
}

// ======================= FAST PATH (counting-sort binning) =======================

// pass 1: per-(block,bucket) histogram of dst only. hist[block*nb + b].
template <bool VEC>
__global__ __launch_bounds__(1024) void k_hist(
    const int* __restrict__ dst, int* __restrict__ hist, int E, int N, int nb, int epb) {
    __shared__ int h[NB_MAX];
    int tid = threadIdx.x;
    for (int b = tid; b < nb; b += 1024) h[b] = 0;
    __syncthreads();
    int start = blockIdx.x * epb;
    int end = min(E, start + epb);
    for (int e0 = start + tid * 4; e0 < end; e0 += 4096) {
        if (VEC && (e0 + 3 < end)) {
            int4 d4 = *reinterpret_cast<const int4*>(dst + e0);
            if ((unsigned)d4.x < (unsigned)N) atomicAdd(&h[(unsigned)d4.x / (unsigned)NPB], 1);
            if ((unsigned)d4.y < (unsigned)N) atomicAdd(&h[(unsigned)d4.y / (unsigned)NPB], 1);
            if ((unsigned)d4.z < (unsigned)N) atomicAdd(&h[(unsigned)d4.z / (unsigned)NPB], 1);
            if ((unsigned)d4.w < (unsigned)N) atomicAdd(&h[(unsigned)d4.w / (unsigned)NPB], 1);
        } else {
            for (int e = e0; e < end && e < e0 + 4; ++e) {
                unsigned du = (unsigned)dst[e];
                if (du < (unsigned)N) atomicAdd(&h[du / (unsigned)NPB], 1);
            }
        }
    }
    __syncthreads();
    int* hrow = hist + (size_t)blockIdx.x * nb;
    for (int b = tid; b < nb; b += 1024) hrow[b] = h[b];
}

// scan: one wave per bucket; prefix over 256 block counts (in place).
__global__ __launch_bounds__(256) void k_scan(
    int* __restrict__ hist, int* __restrict__ counts, int nb, int cap) {
    int wid = blockIdx.x * 4 + (threadIdx.x >> 6);   // bucket id
    int lane = threadIdx.x & 63;
    if (wid >= nb) return;
    int v0 = hist[(size_t)(lane * 4 + 0) * nb + wid];
    int v1 = hist[(size_t)(lane * 4 + 1) * nb + wid];
    int v2 = hist[(size_t)(lane * 4 + 2) * nb + wid];
    int v3 = hist[(size_t)(lane * 4 + 3) * nb + wid];
    int s = v0 + v1 + v2 + v3;
    int e = s;
    #pragma unroll
    for (int off = 1; off < 64; off <<= 1) {
        int t = __shfl_up(e, off, 64);
        if (lane >= off) e += t;
    }
    int total = __shfl(e, 63, 64);
    e -= s;                                           // exclusive prefix
    int p = wid * cap + e;
    hist[(size_t)(lane * 4 + 0) * nb + wid] = p; p += v0;
    hist[(size_t)(lane * 4 + 1) * nb + wid] = p; p += v1;
    hist[(size_t)(lane * 4 + 2) * nb + wid] = p; p += v2;
    hist[(size_t)(lane * 4 + 3) * nb + wid] = p;
    if (lane == 0) counts[wid] = total;
}

// pass 2: place edges; cursors in LDS (pre-reserved exact regions).
__device__ __forceinline__ void bin_one2(int dd, int ss, int N,
                                         unsigned* stage, int* lcnt, int* lcur,
                                         unsigned* __restrict__ binned, int cap) {
    unsigned du = (unsigned)dd;
    if (du < (unsigned)N) {
        unsigned su = (unsigned)ss;
        if (su >= (unsigned)N) su = (unsigned)(N - 1);   // defensive clamp
        unsigned b  = du / (unsigned)NPB;
        unsigned lo = du - b * (unsigned)NPB;
        unsigned pk = (lo << SRC_BITS) | su;
        int idx = atomicAdd(&lcnt[b], 1);
        if (idx < SCAP) {
            stage[b * SCAP_P + idx] = pk;
        } else {                      // rare in-batch overflow: direct place
            int pos = atomicAdd(&lcur[b], 1);
            if (pos < (int)((b + 1) * (unsigned)cap)) binned[pos] = pk;
        }
    }
}

__device__ __forceinline__ void bin_flush2(unsigned* stage, int* lcnt, int* lcur,
                                           unsigned* __restrict__ binned,
                                           int nb, int cap, bool drain, int tid) {
    for (int b = tid; b < nb; b += 1024) {
        int c = lcnt[b];
        int valid = c < SCAP ? c : SCAP;
        int cntf = drain ? valid : (valid & ~(FCHUNK - 1));
        if (cntf > 0) {
            int pos = atomicAdd(&lcur[b], cntf);
            int lim = (b + 1) * cap;
            unsigned* s = stage + b * SCAP_P;
            int k = 0;
            if (pos + cntf <= lim) {
                int head = (4 - (pos & 3)) & 3;
                if (head > cntf) head = cntf;
                for (; k < head; ++k) binned[pos + k] = s[k];
                for (; k + 4 <= cntf; k += 4) {
                    uint4 v; v.x = s[k]; v.y = s[k + 1]; v.z = s[k + 2]; v.w = s[k + 3];
                    *reinterpret_cast<uint4*>(binned + pos + k) = v;
                }
                for (; k < cntf; ++k) binned[pos + k] = s[k];
            } else {
                for (; k < cntf; ++k)
                    if (pos + k < lim) binned[pos + k] = s[k];
            }
            int rem = valid - cntf;
            for (int kk = 0; kk < rem; ++kk) s[kk] = s[cntf + kk];
            lcnt[b] = rem;
        }
    }
}

template <bool VEC>
__global__ __launch_bounds__(1024) void k_bin2(
    const int* __restrict__ src, const int* __restrict__ dst,
    unsigned* __restrict__ binned, const int* __restrict__ offs,
    int E, int N, int cap, int nb, int epb) {
    __shared__ unsigned stage[NB_MAX * SCAP_P];   // 136 KB (padded)
    __shared__ int lcnt[NB_MAX];                  // 8 KB
    __shared__ int lcur[NB_MAX];                  // 8 KB
    int tid = threadIdx.x;
    const int* orow = offs + (size_t)blockIdx.x * nb;
    for (int b = tid; b < nb; b += 1024) { lcnt[b] = 0; lcur[b] = orow[b]; }
    __syncthreads();
    int start = blockIdx.x * epb;
    int end = min(E, start + epb);
    if (start >= end) return;   // uniform across block

    int e_cur = start + tid * 4;
    int4 s_cur, d_cur;
    bool v_cur = VEC && (e_cur + 3 < end);
    if (v_cur) {
        s_cur = *reinterpret_cast<const int4*>(src + e_cur);
        d_cur = *reinterpret_cast<const int4*>(dst + e_cur);
    }
    for (int base_e = start; base_e < end; base_e += 4096) {
        int e_nxt = e_cur + 4096;
        int4 s_nxt, d_nxt;
        bool v_nxt = VEC && (base_e + 4096 < end) && (e_nxt + 3 < end);
        if (v_nxt) {
            s_nxt = *reinterpret_cast<const int4*>(src + e_nxt);
            d_nxt = *reinterpret_cast<const int4*>(dst + e_nxt);
        }
        if (e_cur < end) {
            if (v_cur) {
                bin_one2(d_cur.x, s_cur.x, N, stage, lcnt, lcur, binned, cap);
                bin_one2(d_cur.y, s_cur.y, N, stage, lcnt, lcur, binned, cap);
                bin_one2(d_cur.z, s_cur.z, N, stage, lcnt, lcur, binned, cap);
                bin_one2(d_cur.w, s_cur.w, N, stage, lcnt, lcur, binned, cap);
            } else {
                for (int e = e_cur; e < end && e < e_cur + 4; ++e)
                    bin_one2(dst[e], src[e], N, stage, lcnt, lcur, binned, cap);
            }
        }
        __syncthreads();
        bool last = (base_e + 4096 >= end);
        bin_flush2(stage, lcnt, lcur, binned, nb, cap, last, tid);
        __syncthreads();
        e_cur = e_nxt; s_cur = s_nxt; d_cur = d_nxt; v_cur = v_nxt;
    }
}

// ---------- consumers (one block per bucket, 16-edge deep-MLP loops) ----------

__global__ __launch_bounds__(256) void k_deg(
    const unsigned* __restrict__ binned, const int* __restrict__ counts,
    const void* __restrict__ xp, float* __restrict__ dinv, bf16* __restrict__ normx,
    int N, int cap, const int* __restrict__ flag) {
    __shared__ int ideg[NPB];
    int b = blockIdx.x, tid = threadIdx.x;
    for (int i = tid; i < NPB; i += 256) ideg[i] = 1;   // self-loop
    __syncthreads();
    int base = b * cap;
    int cnt = min(counts[b], cap);
    int cv = cnt & ~15;
    for (int i = tid * 16; i < cv; i += 4096) {
        const uint4* bp = reinterpret_cast<const uint4*>(binned + base + i);
        uint4 p0 = bp[0], p1 = bp[1], p2 = bp[2], p3 = bp[3];
        atomicAdd(&ideg[p0.x >> SRC_BITS], 1); atomicAdd(&ideg[p0.y >> SRC_BITS], 1);
        atomicAdd(&ideg[p0.z >> SRC_BITS], 1); atomicAdd(&ideg[p0.w >> SRC_BITS], 1);
        atomicAdd(&ideg[p1.x >> SRC_BITS], 1); atomicAdd(&ideg[p1.y >> SRC_BITS], 1);
        atomicAdd(&ideg[p1.z >> SRC_BITS], 1); atomicAdd(&ideg[p1.w >> SRC_BITS], 1);
        atomicAdd(&ideg[p2.x >> SRC_BITS], 1); atomicAdd(&ideg[p2.y >> SRC_BITS], 1);
        atomicAdd(&ideg[p2.z >> SRC_BITS], 1); atomicAdd(&ideg[p2.w >> SRC_BITS], 1);
        atomicAdd(&ideg[p3.x >> SRC_BITS], 1); atomicAdd(&ideg[p3.y >> SRC_BITS], 1);
        atomicAdd(&ideg[p3.z >> SRC_BITS], 1); atomicAdd(&ideg[p3.w >> SRC_BITS], 1);
    }
    for (int i = cv + tid; i < cnt; i += 256)
        atomicAdd(&ideg[binned[base + i] >> SRC_BITS], 1);
    __syncthreads();
    bool isb = (*flag) != 0;
    long node0 = (long)b * NPB;
    for (int i = tid; i < NPB; i += 256) {
        long node = node0 + i;
        if (node < N) {
            float di = rsqrtf((float)ideg[i]);
            float xv = isb ? bf2f(((const bf16*)xp)[node]) : ((const float*)xp)[node];
            dinv[node] = di;
            normx[node] = __float2bfloat16(di * xv);
        }
    }
}

// 16-edge gather+accumulate macro body shared by agg1/agg2
#define GATHER16(VALARR)                                                         \
    const uint4* bp = reinterpret_cast<const uint4*>(binned + base + i);         \
    uint4 p0 = bp[0], p1 = bp[1], p2 = bp[2], p3 = bp[3];                        \
    float g0  = bf2f(VALARR[p0.x & SRC_MASK]);                                   \
    float g1  = bf2f(VALARR[p0.y & SRC_MASK]);                                   \
    float g2  = bf2f(VALARR[p0.z & SRC_MASK]);                                   \
    float g3  = bf2f(VALARR[p0.w & SRC_MASK]);                                   \
    float g4  = bf2f(VALARR[p1.x & SRC_MASK]);                                   \
    float g5  = bf2f(VALARR[p1.y & SRC_MASK]);                                   \
    float g6  = bf2f(VALARR[p1.z & SRC_MASK]);                                   \
    float g7  = bf2f(VALARR[p1.w & SRC_MASK]);                                   \
    float g8  = bf2f(VALARR[p2.x & SRC_MASK]);                                   \
    float g9  = bf2f(VALARR[p2.y & SRC_MASK]);                                   \
    float g10 = bf2f(VALARR[p2.z & SRC_MASK]);                                   \
    float g11 = bf2f(VALARR[p2.w & SRC_MASK]);                                   \
    float g12 = bf2f(VALARR[p3.x & SRC_MASK]);                                   \
    float g13 = bf2f(VALARR[p3.y & SRC_MASK]);                                   \
    float g14 = bf2f(VALARR[p3.z & SRC_MASK]);                                   \
    float g15 = bf2f(VALARR[p3.w & SRC_MASK]);                                   \
    atomicAdd(&acc[p0.x >> SRC_BITS], g0);                                       \
    atomicAdd(&acc[p0.y >> SRC_BITS], g1);                                       \
    atomicAdd(&acc[p0.z >> SRC_BITS], g2);                                       \
    atomicAdd(&acc[p0.w >> SRC_BITS], g3);                                       \
    atomicAdd(&acc[p1.x >> SRC_BITS], g4);                                       \
    atomicAdd(&acc[p1.y >> SRC_BITS], g5);                                       \
    atomicAdd(&acc[p1.z >> SRC_BITS], g6);                                       \
    atomicAdd(&acc[p1.w >> SRC_BITS], g7);                                       \
    atomicAdd(&acc[p2.x >> SRC_BITS], g8);                                       \
    atomicAdd(&acc[p2.y >> SRC_BITS], g9);                                       \
    atomicAdd(&acc[p2.z >> SRC_BITS], g10);                                      \
    atomicAdd(&acc[p2.w >> SRC_BITS], g11);                                      \
    atomicAdd(&acc[p3.x >> SRC_BITS], g12);                                      \
    atomicAdd(&acc[p3.y >> SRC_BITS], g13);                                      \
    atomicAdd(&acc[p3.z >> SRC_BITS], g14);                                      \
    atomicAdd(&acc[p3.w >> SRC_BITS], g15);

__global__ __launch_bounds__(256) void k_agg1(
    const unsigned* __restrict__ binned, const int* __restrict__ counts,
    const float* __restrict__ dinv, const bf16* __restrict__ normx,
    bf16* __restrict__ normh,
    const void* __restrict__ W1p, const void* __restrict__ b1p,
    const void* __restrict__ W2p, int N, int cap, const int* __restrict__ flag) {
    __shared__ float acc[NPB];
    __shared__ float sh_ab[2];
    int b = blockIdx.x, tid = threadIdx.x;
    bool isb = (*flag) != 0;
    if (tid == 0) {
        float a = 0.f, bb = 0.f;
        if (isb) {
            const bf16* W1 = (const bf16*)W1p; const bf16* b1 = (const bf16*)b1p;
            const bf16* W2 = (const bf16*)W2p;
            #pragma unroll
            for (int k = 0; k < 16; ++k) {
                float w2 = bf2f(W2[k]);
                a += bf2f(W1[k]) * w2;
                bb += bf2f(b1[k]) * w2;
            }
        } else {
            const float* W1 = (const float*)W1p; const float* b1 = (const float*)b1p;
            const float* W2 = (const float*)W2p;
            #pragma unroll
            for (int k = 0; k < 16; ++k) { a += W1[k] * W2[k]; bb += b1[k] * W2[k]; }
        }
        sh_ab[0] = a; sh_ab[1] = bb;
    }
    for (int i = tid; i < NPB; i += 256) acc[i] = 0.f;
    __syncthreads();
    int base = b * cap;
    int cnt = min(counts[b], cap);
    int cv = cnt & ~15;
    for (int i = tid * 16; i < cv; i += 4096) { GATHER16(normx) }
    for (int i = cv + tid; i < cnt; i += 256) {
        unsigned p = binned[base + i];
        atomicAdd(&acc[p >> SRC_BITS], bf2f(normx[p & SRC_MASK]));
    }
    __syncthreads();
    float alpha = sh_ab[0], beta = sh_ab[1];
    long node0 = (long)b * NPB;
    for (int i = tid; i < NPB; i += 256) {
        long node = node0 + i;
        if (node < N) {
            float di = dinv[node];
            float s1 = bf2f(normx[node]) + acc[i];       // self + neighbors
            float h2 = fmaf(alpha, di * s1, beta);       // layer-2 pre-act
            normh[node] = __float2bfloat16(di * h2);
        }
    }
}

// layer-2 aggregation + fused classifier with j-vectorized GEMV (1 image/block)
__global__ __launch_bounds__(256) void k_agg2c(
    const unsigned* __restrict__ binned, const int* __restrict__ counts,
    const float* __restrict__ dinv, const bf16* __restrict__ normh,
    const void* __restrict__ b2p,
    const void* __restrict__ Wlinp, const void* __restrict__ blinp,
    const void* __restrict__ Wclsp, const void* __restrict__ bclsp,
    void* __restrict__ outp, int N, int cap, int B, const int* __restrict__ flag) {
    __shared__ float acc[NPB];          // neighbor sums -> v
    __shared__ float zpart[16][128];    // k-group partials
    __shared__ float z[128];
    __shared__ float lg[10];
    int b = blockIdx.x, tid = threadIdx.x;
    bool isb = (*flag) != 0;
    for (int i = tid; i < NPB; i += 256) acc[i] = 0.f;
    __syncthreads();
    int base = b * cap;
    int cnt = min(counts[b], cap);
    int cv = cnt & ~15;
    for (int i = tid * 16; i < cv; i += 4096) { GATHER16(normh) }
    for (int i = cv + tid; i < cnt; i += 256) {
        unsigned p = binned[base + i];
        atomicAdd(&acc[p >> SRC_BITS], bf2f(normh[p & SRC_MASK]));
    }
    __syncthreads();
    float bias2 = isb ? bf2f(((const bf16*)b2p)[0]) : ((const float*)b2p)[0];
    long node0 = (long)b * NPB;
    for (int i = tid; i < NPB; i += 256) {
        long node = node0 + i;
        float vv = 0.f;
        if (node < N) {
            float di = dinv[node];
            float s2 = bf2f(normh[node]) + acc[i];
            vv = fmaf(di, s2, bias2);                    // v = agg2 + b2
        }
        acc[i] = vv;
    }
    __syncthreads();
    // GEMV 784->128: 16 j-groups (8 consecutive j, 16B W loads) x 16 k-groups (49 k)
    {
        int jg = tid & 15, kg = tid >> 4;
        int j8 = jg * 8;
        float p0 = 0.f, p1 = 0.f, p2 = 0.f, p3 = 0.f;
        float p4 = 0.f, p5 = 0.f, p6 = 0.f, p7 = 0.f;
        int k0 = kg * 49, k1 = k0 + 49;
        if (isb) {
            const bf16* W = (const bf16*)Wlinp;
            for (int k = k0; k < k1; ++k) {
                uint4 u = *reinterpret_cast<const uint4*>(W + (size_t)k * 128 + j8);
                float vk = acc[k];
                p0 = fmaf(vk, __uint_as_float(u.x << 16), p0);
                p1 = fmaf(vk, __uint_as_float(u.x & 0xFFFF0000u), p1);
                p2 = fmaf(vk, __uint_as_float(u.y << 16), p2);
                p3 = fmaf(vk, __uint_as_float(u.y & 0xFFFF0000u), p3);
                p4 = fmaf(vk, __uint_as_float(u.z << 16), p4);
                p5 = fmaf(vk, __uint_as_float(u.z & 0xFFFF0000u), p5);
                p6 = fmaf(vk, __uint_as_float(u.w << 16), p6);
                p7 = fmaf(vk, __uint_as_float(u.w & 0xFFFF0000u), p7);
            }
        } else {
            const float* W = (const float*)Wlinp;
            for (int k = k0; k < k1; ++k) {
                float4 wa = *reinterpret_cast<const float4*>(W + (size_t)k * 128 + j8);
                float4 wb = *reinterpret_cast<const float4*>(W + (size_t)k * 128 + j8 + 4);
                float vk = acc[k];
                p0 = fmaf(vk, wa.x, p0); p1 = fmaf(vk, wa.y, p1);
                p2 = fmaf(vk, wa.z, p2); p3 = fmaf(vk, wa.w, p3);
                p4 = fmaf(vk, wb.x, p4); p5 = fmaf(vk, wb.y, p5);
                p6 = fmaf(vk, wb.z, p6); p7 = fmaf(vk, wb.w, p7);
            }
        }
        zpart[kg][j8 + 0] = p0; zpart[kg][j8 + 1] = p1;
        zpart[kg][j8 + 2] = p2; zpart[kg][j8 + 3] = p3;
        zpart[kg][j8 + 4] = p4; zpart[kg][j8 + 5] = p5;
        zpart[kg][j8 + 6] = p6; zpart[kg][j8 + 7] = p7;
    }
    __syncthreads();
    if (tid < 128) {
        float s = isb ? bf2f(((const bf16*)blinp)[tid]) : ((const float*)blinp)[tid];
        #pragma unroll
        for (int kg = 0; kg < 16; ++kg) s += zpart[kg][tid];
        z[tid] = fmaxf(s, 0.f);
    }
    __syncthreads();
    if (tid < 10) {
        float l = isb ? bf2f(((const bf16*)bclsp)[tid]) : ((const float*)bclsp)[tid];
        if (isb) {
            const bf16* W = (const bf16*)Wclsp;
            #pragma unroll 8
            for (int jj = 0; jj < 128; ++jj) l = fmaf(z[jj], bf2f(W[jj * 10 + tid]), l);
        } else {
            const float* W = (const float*)Wclsp;
            #pragma unroll 8
            for (int jj = 0; jj < 128; ++jj) l = fmaf(z[jj], W[jj * 10 + tid], l);
        }
        lg[tid] = l;
    }
    __syncthreads();
    if (tid == 0 && b < B) {
        float m = -1e30f;
        #pragma unroll
        for (int c = 0; c < 10; ++c) m = fmaxf(m, lg[c]);
        float se = 0.f;
        #pragma unroll
        for (int c = 0; c < 10; ++c) se += expf(lg[c] - m);
        float lse = m + logf(se);
        long ob = (long)b * 10;
        if (isb) {
            bf16* o = (bf16*)outp;
            #pragma unroll
            for (int c = 0; c < 10; ++c) o[ob + c] = __float2bfloat16(lg[c] - lse);
        } else {
            float* o = (float*)outp;
            #pragma unroll
            for (int c = 0; c < 10; ++c) o[ob + c] = lg[c] - lse;
        }
    }
}

// ======================= FALLBACK PATH (round-2, proven) =======================

__global__ void k_init(float* __restrict__ deg, int n) {
    int i = blockIdx.x * blockDim.x + threadIdx.x;
    if (i < n) deg[i] = 1.0f;
}

__global__ void k_node_a(float* __restrict__ deg_dinv, const void* __restrict__ xp,
                         bf16* __restrict__ normx, float* __restrict__ s1, int n,
                         const int* __restrict__ flag) {
    int i = blockIdx.x * blockDim.x + threadIdx.x;
    bool isb = (*flag) != 0;
    if (i < n) {
        float dg = deg_dinv[i];
        float di = rsqrtf(dg);
        float xv = isb ? bf2f(((const bf16*)xp)[i]) : ((const float*)xp)[i];
        float nx = di * xv;
        deg_dinv[i] = di;
        normx[i] = __float2bfloat16(nx);
        s1[i] = nx;
    }
}

__global__ void k_node_b(const float* __restrict__ dinv, bf16* __restrict__ normh,
                         float* __restrict__ s, const void* __restrict__ W1p,
                         const void* __restrict__ b1p, const void* __restrict__ W2p,
                         int n, const int* __restrict__ flag) {
    __shared__ float sh_ab[2];
    bool isb = (*flag) != 0;
    if (threadIdx.x == 0) {
        float a = 0.f, b = 0.f;
        if (isb) {
            const bf16* W1 = (const bf16*)W1p; const bf16* b1 = (const bf16*)b1p;
            const bf16* W2 = (const bf16*)W2p;
            #pragma unroll
            for (int k = 0; k < 16; ++k) {
                float w2 = bf2f(W2[k]);
                a += bf2f(W1[k]) * w2;
                b += bf2f(b1[k]) * w2;
            }
        } else {
            const float* W1 = (const float*)W1p; const float* b1 = (const float*)b1p;
            const float* W2 = (const float*)W2p;
            #pragma unroll
            for (int k = 0; k < 16; ++k) { a += W1[k] * W2[k]; b += b1[k] * W2[k]; }
        }
        sh_ab[0] = a; sh_ab[1] = b;
    }
    __syncthreads();
    float alpha = sh_ab[0], beta = sh_ab[1];
    int i = blockIdx.x * blockDim.x + threadIdx.x;
    if (i < n) {
        float di = dinv[i];
        float agg1 = di * s[i];
        float h2 = fmaf(alpha, agg1, beta);
        float nh = di * h2;
        normh[i] = __float2bfloat16(nh);
        s[i] = nh;
    }
}

template <bool VEC>
__global__ void k_count(const int* __restrict__ dst, float* __restrict__ deg, int E, int N) {
    int t = blockIdx.x * blockDim.x + threadIdx.x;
    int e0 = t * 4;
    if (VEC && (e0 + 3 < E)) {
        int4 d = *reinterpret_cast<const int4*>(dst + e0);
        if ((unsigned)d.x < (unsigned)N) atomicAdd(deg + d.x, 1.0f);
        if ((unsigned)d.y < (unsigned)N) atomicAdd(deg + d.y, 1.0f);
        if ((unsigned)d.z < (unsigned)N) atomicAdd(deg + d.z, 1.0f);
        if ((unsigned)d.w < (unsigned)N) atomicAdd(deg + d.w, 1.0f);
    } else {
        for (int e = e0; e < E && e < e0 + 4; ++e) {
            int d = dst[e];
            if ((unsigned)d < (unsigned)N) atomicAdd(deg + d, 1.0f);
        }
    }
}

template <bool VEC>
__global__ void k_scatter(const int* __restrict__ src, const int* __restrict__ dstp,
                          const bf16* __restrict__ val, float* __restrict__ acc,
                          int E, int N) {
    int t = blockIdx.x * blockDim.x + threadIdx.x;
    int e0 = t * 4;
    if (VEC && (e0 + 3 < E)) {
        int4 s = *reinterpret_cast<const int4*>(src + e0);
        int4 d = *reinterpret_cast<const int4*>(dstp + e0);
        float v0 = ((unsigned)s.x < (unsigned)N) ? bf2f(val[s.x]) : 0.f;
        float v1 = ((unsigned)s.y < (unsigned)N) ? bf2f(val[s.y]) : 0.f;
        float v2 = ((unsigned)s.z < (unsigned)N) ? bf2f(val[s.z]) : 0.f;
        float v3 = ((unsigned)s.w < (unsigned)N) ? bf2f(val[s.w]) : 0.f;
        if ((unsigned)d.x < (unsigned)N) atomicAdd(acc + d.x, v0);
        if ((unsigned)d.y < (unsigned)N) atomicAdd(acc + d.y, v1);
        if ((unsigned)d.z < (unsigned)N) atomicAdd(acc + d.z, v2);
        if ((unsigned)d.w < (unsigned)N) atomicAdd(acc + d.w, v3);
    } else {
        for (int e = e0; e < E && e < e0 + 4; ++e) {
            int sI = src[e], dI = dstp[e];
            if ((unsigned)sI < (unsigned)N && (unsigned)dI < (unsigned)N)
                atomicAdd(acc + dI, bf2f(val[sI]));
        }
    }
}

#define IMG 8
__global__ __launch_bounds__(256) void k_cls(
    const float* __restrict__ dinv, const float* __restrict__ s2,
    const void* __restrict__ b2p,
    const void* __restrict__ Wlinp, const void* __restrict__ blinp,
    const void* __restrict__ Wclsp, const void* __restrict__ bclsp,
    void* __restrict__ outp, int B, long Ntot, const int* __restrict__ flag) {
    __shared__ __align__(16) float v[784 * IMG];
    __shared__ float z[IMG][128];
    __shared__ float lg[IMG * 10];
    int tid = threadIdx.x;
    int b0 = blockIdx.x * IMG;
    bool isb = (*flag) != 0;
    float bias2 = isb ? bf2f(((const bf16*)b2p)[0]) : ((const float*)b2p)[0];
    long base = (long)b0 * 784;

    for (int idx = tid; idx < 784 * IMG; idx += 256) {
        int img = idx / 784;
        int k = idx - img * 784;
        long node = base + (long)img * 784 + k;
        float val = 0.f;
        if (node < Ntot) val = fmaf(dinv[node], s2[node], bias2);
        v[k * IMG + img] = val;
    }
    __syncthreads();

    int j = tid & 127;
    int half = tid >> 7;
    float bj = isb ? bf2f(((const bf16*)blinp)[j]) : ((const float*)blinp)[j];
    float a0 = bj, a1 = bj, a2 = bj, a3 = bj;
    const float4* v4 = reinterpret_cast<const float4*>(v);
    if (isb) {
        const bf16* Wlin = (const bf16*)Wlinp;
        #pragma unroll 4
        for (int k = 0; k < 784; ++k) {
            float w = bf2f(Wlin[k * 128 + j]);
            float4 vk = v4[k * 2 + half];
            a0 = fmaf(vk.x, w, a0); a1 = fmaf(vk.y, w, a1);
            a2 = fmaf(vk.z, w, a2); a3 = fmaf(vk.w, w, a3);
        }
    } else {
        const float* Wlin = (const float*)Wlinp;
        #pragma unroll 4
        for (int k = 0; k < 784; ++k) {
            float w = Wlin[k * 128 + j];
            float4 vk = v4[k * 2 + half];
            a0 = fmaf(vk.x, w, a0); a1 = fmaf(vk.y, w, a1);
            a2 = fmaf(vk.z, w, a2); a3 = fmaf(vk.w, w, a3);
        }
    }
    int ib = half * 4;
    z[ib + 0][j] = fmaxf(a0, 0.f);
    z[ib + 1][j] = fmaxf(a1, 0.f);
    z[ib + 2][j] = fmaxf(a2, 0.f);
    z[ib + 3][j] = fmaxf(a3, 0.f);
    __syncthreads();

    if (tid < IMG * 10) {
        int img = tid / 10, c = tid - img * 10;
        float l;
        if (isb) {
            const bf16* Wcls = (const bf16*)Wclsp;
            l = bf2f(((const bf16*)bclsp)[c]);
            #pragma unroll 8
            for (int jj = 0; jj < 128; ++jj) l = fmaf(z[img][jj], bf2f(Wcls[jj * 10 + c]), l);
        } else {
            const float* Wcls = (const float*)Wclsp;
            l = ((const float*)bclsp)[c];
            #pragma unroll 8
            for (int jj = 0; jj < 128; ++jj) l = fmaf(z[img][jj], Wcls[jj * 10 + c], l);
        }
        lg[tid] = l;
    }
    __syncthreads();

    if (tid < IMG && (b0 + tid) < B) {
        float m = -1e30f;
        #pragma unroll
        for (int c = 0; c < 10; ++c) m = fmaxf(m, lg[tid * 10 + c]);
        float se = 0.f;
        #pragma unroll
        for (int c = 0; c < 10; ++c) se += expf(lg[tid * 10 + c] - m);
        float lse = m + logf(se);
        long ob = (long)(b0 + tid) * 10;
        if (isb) {
            bf16* out = (bf16*)outp;
            #pragma unroll
            for (int c = 0; c < 10; ++c) out[ob + c] = __float2bfloat16(lg[tid * 10 + c] - lse);
        } else {
            float* out = (float*)outp;
            #pragma unroll
            for (int c = 0; c < 10; ++c) out[ob + c] = lg[tid * 10 + c] - lse;
        }
    }
}

// ======================= launcher =======================

extern "C" void kernel_launch(void* const* d_in, const int* in_sizes, int n_in,
                              void* d_out, int out_size, void* d_ws, size_t ws_size,
                              hipStream_t stream) {
    const void* x    = d_in[0];
    const int*  ei   = (const int*)d_in[1];
    const void* W1   = d_in[2];
    const void* b1   = d_in[3];
    const void* W2   = d_in[4];
    const void* b2   = d_in[5];
    const void* Wlin = d_in[6];
    const void* blin = d_in[7];
    const void* Wcls = d_in[8];
    const void* bcls = d_in[9];

    const int N = in_sizes[0];
    const int E = in_sizes[1] / 2;
    const int B = N / NPB;
    const int nb = (N + NPB - 1) / NPB;

    // exact counting-sort; cap = mean + 10% + 16, rounded down to mult of 4
    const long mean = (nb > 0) ? (long)E / nb : 0;
    const int cap = (int)((mean + mean / 10 + 16) & ~3L);

    const int* src = ei;
    const int* dst = ei + E;
    const bool vec = ((E & 3) == 0);
    const int eblk = ((E + 3) / 4 + 255) / 256;

    // fast-path workspace layout
    size_t off = 256;  // flag
    size_t cnt_off = off;  off += (size_t)nb * 4;        off = (off + 255) & ~255ull;
    size_t dinv_off = off; off += (size_t)N * 4;         off = (off + 255) & ~255ull;
    size_t nx_off = off;   off += (size_t)N * 2;         off = (off + 255) & ~255ull;
    size_t nh_off = off;   off += (size_t)N * 2;         off = (off + 255) & ~255ull;
    size_t hist_off = off; off += (size_t)BINBLK * nb * 4; off = (off + 255) & ~255ull;
    size_t bin_off = off;  off += (size_t)nb * (size_t)cap * 4;

    const bool cap_ok = (double)cap >= (double)mean + 8.0 * sqrt((double)(mean > 0 ? mean : 1));
    const bool fast = (N < (1 << SRC_BITS)) && (nb <= NB_MAX) && (ws_size >= off) && cap_ok;

    int* flag = (int*)d_ws;
    k_detect<<<1, 64, 0, stream>>>((const unsigned short*)x, flag);

    if (fast) {
        int*      counts = (int*)((char*)d_ws + cnt_off);
        float*    dinv   = (float*)((char*)d_ws + dinv_off);
        bf16*     normx  = (bf16*)((char*)d_ws + nx_off);
        bf16*     normh  = (bf16*)((char*)d_ws + nh_off);
        int*      hist   = (int*)((char*)d_ws + hist_off);
        unsigned* binned = (unsigned*)((char*)d_ws + bin_off);

        const int epb = (((E + BINBLK - 1) / BINBLK) + 3) & ~3;   // mult of 4

        if (vec) k_hist<true ><<<BINBLK, 1024, 0, stream>>>(dst, hist, E, N, nb, epb);
        else     k_hist<false><<<BINBLK, 1024, 0, stream>>>(dst, hist, E, N, nb, epb);
        k_scan<<<(nb + 3) / 4, 256, 0, stream>>>(hist, counts, nb, cap);
        if (vec) k_bin2<true ><<<BINBLK, 1024, 0, stream>>>(src, dst, binned, hist,
                                                            E, N, cap, nb, epb);
        else     k_bin2<false><<<BINBLK, 1024, 0, stream>>>(src, dst, binned, hist,
                                                            E, N, cap, nb, epb);
        k_deg <<<nb, 256, 0, stream>>>(binned, counts, x, dinv, normx, N, cap, flag);
        k_agg1<<<nb, 256, 0, stream>>>(binned, counts, dinv, normx, normh,
                                       W1, b1, W2, N, cap, flag);
        k_agg2c<<<nb, 256, 0, stream>>>(binned, counts, dinv, normh, b2,
                                        Wlin, blin, Wcls, bcls, d_out, N, cap, B, flag);
    } else {
        float* buf0 = (float*)((char*)d_ws + 256);
        float* buf2 = buf0 + N;
        bf16*  buf1 = (bf16*)(buf2 + N);
        const int nblk = (N + 255) / 256;

        k_init<<<nblk, 256, 0, stream>>>(buf0, N);
        if (vec) k_count<true ><<<eblk, 256, 0, stream>>>(dst, buf0, E, N);
        else     k_count<false><<<eblk, 256, 0, stream>>>(dst, buf0, E, N);
        k_node_a<<<nblk, 256, 0, stream>>>(buf0, x, buf1, buf2, N, flag);
        if (vec) k_scatter<true ><<<eblk, 256, 0, stream>>>(src, dst, buf1, buf2, E, N);
        else     k_scatter<false><<<eblk, 256, 0, stream>>>(src, dst, buf1, buf2, E, N);
        k_node_b<<<nblk, 256, 0, stream>>>(buf0, buf1, buf2, W1, b1, W2, N, flag);
        if (vec) k_scatter<true ><<<eblk, 256, 0, stream>>>(src, dst, buf1, buf2, E, N);
        else     k_scatter<false><<<eblk, 256, 0, stream>>>(src, dst, buf1, buf2, E, N);
        k_cls<<<(B + IMG - 1) / IMG, 256, 0, stream>>>(buf0, buf2, b2, Wlin, blin,
                                                       Wcls, bcls, d_out, B, (long)N, flag);
    }
}